// Round 2
// 933.244 us; speedup vs baseline: 1.2835x; 1.2835x over previous
//
#include <hip/hip_runtime.h>
#include <stdint.h>

typedef unsigned short u16;
typedef unsigned int   u32;
typedef unsigned long long u64;
typedef __attribute__((ext_vector_type(8))) short short8;
typedef __attribute__((ext_vector_type(4))) short s16x4;
typedef __attribute__((ext_vector_type(4))) float f32x4;

#define B_    8
#define S_    1024
#define HID_  1024
#define NH_   16
#define HD_   64
#define E_    8
#define IDIM_ 128
#define NTOK  (B_*NH_*S_)   /* 131072 */

// ---------- helpers ----------
__device__ __forceinline__ float bf2f(u16 u){ return __uint_as_float(((u32)u) << 16); }
__device__ __forceinline__ u16 f2bf(float f){
    u32 u = __float_as_uint(f);
    u32 r = u + 0x7fffu + ((u >> 16) & 1u);   // RNE
    return (u16)(r >> 16);
}
// 8 consecutive fp32 -> bf16 MFMA fragment (A or B operand)
__device__ __forceinline__ short8 frag8(const float* __restrict__ p){
    float4 a = *(const float4*)p;
    float4 b = *(const float4*)(p + 4);
    short8 r;
    r[0]=(short)f2bf(a.x); r[1]=(short)f2bf(a.y); r[2]=(short)f2bf(a.z); r[3]=(short)f2bf(a.w);
    r[4]=(short)f2bf(b.x); r[5]=(short)f2bf(b.y); r[6]=(short)f2bf(b.z); r[7]=(short)f2bf(b.w);
    return r;
}
__device__ __forceinline__ float gelu_f(float x){
    return 0.5f * x * (1.0f + erff(x * 0.70710678118654752f));
}

// ---------------- kernel 0: zero counters ----------------
__global__ void k_zero(u32* c){
    if (threadIdx.x < 16) c[threadIdx.x] = 0;
}

// ---------------- kernel 0b: fp32 weights -> bf16 (both natural layout) ----------------
__global__ __launch_bounds__(256) void k_prep(
    const float* __restrict__ W1, const float* __restrict__ W2,
    u16* __restrict__ wB1, u16* __restrict__ wB2)
{
    const int i = blockIdx.x*256 + threadIdx.x;   // grid 256 -> 65536
    wB1[i] = f2bf(W1[i]);                         // [e][j=128][d=64]
    wB2[i] = f2bf(W2[i]);                         // [e][n=64][k=128]
}

// ---------------- kernel 1: MFMA k/v projection + memory cell -> current_memorys ----------------
__global__ __launch_bounds__(256,2) void k_mem(
    const float* __restrict__ kin, const float* __restrict__ vin, const float* __restrict__ mem,
    const float* __restrict__ Wk,  const float* __restrict__ Wv,  const float* __restrict__ fg,
    float* __restrict__ cur_out)
{
    const int lane = threadIdx.x & 63;
    const int wid  = threadIdx.x >> 6;
    const int m    = lane & 15;
    const int kg   = lane >> 4;

    const int slab  = blockIdx.x;
    const int chunk = slab & 3, h = (slab >> 2) & 15, b = slab >> 6;
    const int tw    = chunk*256 + wid*64;

    const float* kbase = kin + ((size_t)b*S_)*HID_ + h*64;
    const float* vbase = vin + ((size_t)b*S_)*HID_ + h*64;

    f32x4 accK[4][4], accV[4][4];
    const f32x4 z = {0.f,0.f,0.f,0.f};
    #pragma unroll
    for (int i=0;i<4;i++){ accK[i][0]=z;accK[i][1]=z;accK[i][2]=z;accK[i][3]=z;
                           accV[i][0]=z;accV[i][1]=z;accV[i][2]=z;accV[i][3]=z; }

    #pragma unroll
    for (int kk=0; kk<2; kk++){
        const int k0 = kk*32 + kg*8;
        short8 aF[4], bF[4];
        #pragma unroll
        for (int mt=0; mt<4; mt++) aF[mt] = frag8(kbase + (size_t)(tw + mt*16 + m)*HID_ + k0);
        #pragma unroll
        for (int ct=0; ct<4; ct++) bF[ct] = frag8(Wk + (ct*16 + m)*64 + k0);
        #pragma unroll
        for (int mt=0; mt<4; mt++)
            #pragma unroll
            for (int ct=0; ct<4; ct++)
                accK[mt][ct] = __builtin_amdgcn_mfma_f32_16x16x32_bf16(aF[mt], bF[ct], accK[mt][ct], 0,0,0);
    }
    #pragma unroll
    for (int kk=0; kk<2; kk++){
        const int k0 = kk*32 + kg*8;
        short8 aF[4], bF[4];
        #pragma unroll
        for (int mt=0; mt<4; mt++) aF[mt] = frag8(vbase + (size_t)(tw + mt*16 + m)*HID_ + k0);
        #pragma unroll
        for (int ct=0; ct<4; ct++) bF[ct] = frag8(Wv + (ct*16 + m)*64 + k0);
        #pragma unroll
        for (int mt=0; mt<4; mt++)
            #pragma unroll
            for (int ct=0; ct<4; ct++)
                accV[mt][ct] = __builtin_amdgcn_mfma_f32_16x16x32_bf16(aF[mt], bF[ct], accV[mt][ct], 0,0,0);
    }

    const size_t nb = ((size_t)(b*NH_ + h)) << 10;
    float fgv[4];
    #pragma unroll
    for (int ct=0; ct<4; ct++) fgv[ct] = fg[ct*16 + m];

    #pragma unroll
    for (int mt=0; mt<4; mt++){
        #pragma unroll
        for (int r=0; r<4; r++){
            const int tok = tw + mt*16 + kg*4 + r;
            const size_t rowo = (nb + (size_t)tok)*64;
            #pragma unroll
            for (int ct=0; ct<4; ct++){
                const int d = ct*16 + m;
                const float kd = accK[mt][ct][r];
                const float vd = accV[mt][ct][r];
                const float f  = fgv[ct];
                const float mv = mem[rowo + d];
                const float cell = kd*vd + f*mv;
                cur_out[rowo + d] = (1.0f - f)*cell + f*mv;
            }
        }
    }
}

// ---------------- kernel 2: MFMA q projection; x = q_*cur -> out0 at final pos ----------------
__global__ __launch_bounds__(256,2) void k_q(
    const float* __restrict__ qin, const float* __restrict__ cur_in, const float* __restrict__ Wq,
    float* __restrict__ out0)
{
    const int lane = threadIdx.x & 63;
    const int wid  = threadIdx.x >> 6;
    const int m    = lane & 15;
    const int kg   = lane >> 4;

    const int slab  = blockIdx.x;
    const int chunk = slab & 3, h = (slab >> 2) & 15, b = slab >> 6;
    const int tw    = chunk*256 + wid*64;

    const float* qbase = qin + ((size_t)b*S_)*HID_ + h*64;

    f32x4 accQ[4][4];
    const f32x4 z = {0.f,0.f,0.f,0.f};
    #pragma unroll
    for (int i=0;i<4;i++){ accQ[i][0]=z;accQ[i][1]=z;accQ[i][2]=z;accQ[i][3]=z; }

    #pragma unroll
    for (int kk=0; kk<2; kk++){
        const int k0 = kk*32 + kg*8;
        short8 aF[4], bF[4];
        #pragma unroll
        for (int mt=0; mt<4; mt++) aF[mt] = frag8(qbase + (size_t)(tw + mt*16 + m)*HID_ + k0);
        #pragma unroll
        for (int ct=0; ct<4; ct++) bF[ct] = frag8(Wq + (ct*16 + m)*64 + k0);
        #pragma unroll
        for (int mt=0; mt<4; mt++)
            #pragma unroll
            for (int ct=0; ct<4; ct++)
                accQ[mt][ct] = __builtin_amdgcn_mfma_f32_16x16x32_bf16(aF[mt], bF[ct], accQ[mt][ct], 0,0,0);
    }

    const size_t nb = ((size_t)(b*NH_ + h)) << 10;
    #pragma unroll
    for (int mt=0; mt<4; mt++){
        #pragma unroll
        for (int r=0; r<4; r++){
            const int tok = tw + mt*16 + kg*4 + r;
            const size_t curo = (nb + (size_t)tok)*64;
            const size_t po   = ((size_t)(b*S_ + tok)*NH_ + h)*64;
            #pragma unroll
            for (int ct=0; ct<4; ct++){
                const int d = ct*16 + m;
                out0[po + d] = accQ[mt][ct][r] * cur_in[curo + d];
            }
        }
    }
}

// ---------------- kernel 3: gate logits + top-2 ----------------
__global__ __launch_bounds__(256,2) void k_gate(
    const float* __restrict__ x_src, const float* __restrict__ gW, const float* __restrict__ gB,
    uint4* __restrict__ topiv, u32* __restrict__ counts)
{
    __shared__ float sGW[512], sGB[8];
    const int tid = threadIdx.x;
    for (int i = tid; i < 512; i += 256) sGW[i] = gW[i];
    if (tid < 8) sGB[tid] = gB[tid];
    __syncthreads();

    const int n = blockIdx.x*256 + tid;
    const int s = n & (S_-1), h = (n >> 10) & (NH_-1), b = n >> 14;
    const size_t po = ((size_t)(b*S_ + s)*NH_ + h)*64;

    float lg[8];
    #pragma unroll
    for (int e = 0; e < 8; e++) lg[e] = sGB[e];

    for (int dc = 0; dc < 16; dc++){
        float4 x4 = ((const float4*)(x_src + po))[dc];
        float xv[4] = {x4.x, x4.y, x4.z, x4.w};
        #pragma unroll
        for (int i = 0; i < 4; i++){
            const int d = dc*4 + i;
            #pragma unroll
            for (int e = 0; e < 8; e++) lg[e] += sGW[e*64 + d] * xv[i];
        }
    }

    int i1 = 0; float v1 = lg[0];
    #pragma unroll
    for (int e = 1; e < 8; e++){ if (lg[e] > v1){ v1 = lg[e]; i1 = e; } }
    int i2 = -1; float v2 = -3.0e38f;
    #pragma unroll
    for (int e = 0; e < 8; e++){ if (e != i1 && lg[e] > v2){ v2 = lg[e]; i2 = e; } }

    topiv[n] = make_uint4((u32)i1, (u32)i2, __float_as_uint(v1), __float_as_uint(v2));

    const int lane = tid & 63;
    for (int e = 0; e < 8; e++){
        u64 m1 = __ballot(i1 == e);
        u64 m2 = __ballot(i2 == e);
        if (lane == 0){
            int c = __popcll(m1) + __popcll(m2);
            if (c) atomicAdd(&counts[e], (u32)c);
        }
    }
}

// ---------------- kernel 4: scatter assignments into compact per-expert lists ----------------
__global__ __launch_bounds__(256,4) void k_scatter(
    const uint4* __restrict__ topiv, const u32* __restrict__ counts, u32* __restrict__ cursors,
    u32* __restrict__ bucket, int2* __restrict__ slots)
{
    const int n = blockIdx.x*256 + threadIdx.x;
    uint4 t = topiv[n];
    const int i1 = (int)t.x, i2 = (int)t.y;

    int off[8]; int acc = 0;
    #pragma unroll
    for (int e = 0; e < 8; e++){ off[e] = acc; acc += (int)counts[e]; }

    const int s = n & (S_-1), h = (n >> 10) & (NH_-1), b = n >> 14;
    const u32 pos32 = (u32)((b*S_ + s)*NH_ + h);

    const int lane = threadIdx.x & 63;
    const u64 low = (1ull << lane) - 1ull;
    int slot1 = 0, slot2 = 0;

    for (int e = 0; e < 8; e++){
        u64 m = __ballot(i1 == e);
        if (i1 == e){
            int leader = __builtin_ctzll(m);
            int base = 0;
            if (lane == leader) base = (int)atomicAdd(&cursors[e], (u32)__popcll(m));
            base = __shfl(base, leader);
            slot1 = off[e] + base + __popcll(m & low);
        }
        u64 m2 = __ballot(i2 == e);
        if (i2 == e){
            int leader = __builtin_ctzll(m2);
            int base = 0;
            if (lane == leader) base = (int)atomicAdd(&cursors[e], (u32)__popcll(m2));
            base = __shfl(base, leader);
            slot2 = off[e] + base + __popcll(m2 & low);
        }
    }
    bucket[slot1] = pos32;
    bucket[slot2] = pos32;
    slots[n] = make_int2(slot1, slot2);
}

// ---------------- kernel 5 (MFMA): compacted expert FFN — simple padded-stride layout ----------------
// Block: 256 threads / 4 waves / 128 tokens of one expert.
// sA1 stride 72 u16 (144 B, 16B-aligned rows, non-pow2 -> bank spread); sH stride 136 u16 (272 B).
// No XOR swizzle, no column permutation: correctness-first version.
__global__ __launch_bounds__(256,2) void k_expert_mfma(
    const float* __restrict__ x_src, const u32* __restrict__ bucket, const u32* __restrict__ counts,
    const u16* __restrict__ wB1, const u16* __restrict__ wB2,
    const float* __restrict__ l1g, const float* __restrict__ l1b,
    const float* __restrict__ l2g, const float* __restrict__ l2b,
    const float* __restrict__ b2,  u16* __restrict__ aout)
{
    const int e = blockIdx.x >> 10;
    const int c = blockIdx.x & 1023;
    const int cnt = (int)counts[e];
    const int aBase = c * 128;
    if (aBase >= cnt) return;     // block-uniform, before any barrier

    int off = 0;
    #pragma unroll
    for (int ee = 0; ee < 8; ee++){ if (ee < e) off += (int)counts[ee]; }

    __shared__ __align__(16) u16 sA1[128*72];    // gelu(LN1(x)) bf16; reused as out tile
    __shared__ __align__(16) u16 sH [128*136];   // gelu(LN2(H)) bf16
    __shared__ float2 sStat[2*128];              // per-row partial {sum,sumsq} per n-half
    __shared__ u32   sPos[128];
    __shared__ float sL1g[64], sL1b[64], sL2g[128], sL2b[128], sB2[64];

    const int tid = threadIdx.x;
    if (tid < 64){ sL1g[tid] = l1g[e*64+tid]; sL1b[tid] = l1b[e*64+tid]; sB2[tid] = b2[e*64+tid]; }
    else if (tid < 192){ int t = tid - 64; sL2g[t] = l2g[e*128+t]; sL2b[t] = l2b[e*128+t]; }
    if (tid < 128){
        int a = aBase + tid; if (a > cnt-1) a = cnt-1;   // clamp tail: duplicate last token
        sPos[tid] = bucket[off + a];
    }
    __syncthreads();

    // ---- phase 1: gather x, LN1, gelu, stage bf16 (16 lanes per token) ----
    {
        const int q = tid & 15;
        #pragma unroll
        for (int it = 0; it < 8; it++){
            const int tok = it*16 + (tid >> 4);
            const u32 pos = sPos[tok];
            float4 x4 = *(const float4*)(x_src + ((size_t)pos << 6) + q*4);
            float s0 = x4.x + x4.y + x4.z + x4.w;
            float s1 = x4.x*x4.x + x4.y*x4.y + x4.z*x4.z + x4.w*x4.w;
            #pragma unroll
            for (int msk = 1; msk < 16; msk <<= 1){
                s0 += __shfl_xor(s0, msk);
                s1 += __shfl_xor(s1, msk);
            }
            const float mu = s0 * (1.0f/64.0f);
            const float rs = rsqrtf(s1 * (1.0f/64.0f) - mu*mu + 1e-5f);
            s16x4 pk;
            pk[0] = (short)f2bf(gelu_f((x4.x - mu)*rs*sL1g[q*4+0] + sL1b[q*4+0]));
            pk[1] = (short)f2bf(gelu_f((x4.y - mu)*rs*sL1g[q*4+1] + sL1b[q*4+1]));
            pk[2] = (short)f2bf(gelu_f((x4.z - mu)*rs*sL1g[q*4+2] + sL1b[q*4+2]));
            pk[3] = (short)f2bf(gelu_f((x4.w - mu)*rs*sL1g[q*4+3] + sL1b[q*4+3]));
            *(s16x4*)(&sA1[tok*72 + q*4]) = pk;
        }
    }
    __syncthreads();

    // ---- phase 2: GEMM1  H[128x128] = A1[128x64] @ W1^T ----
    const int lane = tid & 63;
    const int w    = tid >> 6;
    const int m    = lane & 15;
    const int kg   = lane >> 4;
    const int th   = w >> 1;        // token half (64 rows)
    const int nh   = w & 1;         // n half (64 cols)

    f32x4 acc[4][4];
    const f32x4 z = {0.f,0.f,0.f,0.f};
    #pragma unroll
    for (int i=0;i<4;i++){ acc[i][0]=z;acc[i][1]=z;acc[i][2]=z;acc[i][3]=z; }

    const u16* wB1e = wB1 + e*8192;
    #pragma unroll
    for (int kk = 0; kk < 2; kk++){
        const int k0 = kk*32 + kg*8;
        short8 aF[4], bF[4];
        #pragma unroll
        for (int mt = 0; mt < 4; mt++){
            const int row = th*64 + mt*16 + m;
            aF[mt] = *(const short8*)(&sA1[row*72 + k0]);
        }
        #pragma unroll
        for (int ct = 0; ct < 4; ct++)
            bF[ct] = *(const short8*)(wB1e + (nh*64 + ct*16 + m)*64 + k0);
        #pragma unroll
        for (int mt = 0; mt < 4; mt++)
            #pragma unroll
            for (int ct = 0; ct < 4; ct++)
                acc[mt][ct] = __builtin_amdgcn_mfma_f32_16x16x32_bf16(aF[mt], bF[ct], acc[mt][ct], 0,0,0);
    }

    // ---- phase 3: LN2 stats — per-row partials over this wave's 64 cols ----
    #pragma unroll
    for (int mt = 0; mt < 4; mt++){
        #pragma unroll
        for (int r = 0; r < 4; r++){
            float v0 = acc[mt][0][r], v1 = acc[mt][1][r], v2 = acc[mt][2][r], v3 = acc[mt][3][r];
            float p0 = (v0+v1)+(v2+v3);
            float p1 = (v0*v0+v1*v1)+(v2*v2+v3*v3);
            #pragma unroll
            for (int msk = 1; msk < 16; msk <<= 1){
                p0 += __shfl_xor(p0, msk);
                p1 += __shfl_xor(p1, msk);
            }
            if (m == 0){
                const int row = th*64 + mt*16 + kg*4 + r;
                sStat[nh*128 + row] = make_float2(p0, p1);
            }
        }
    }
    __syncthreads();

    // ---- phase 4: gelu(LN2(H)) -> sH bf16 (scalar stores, logical col order) ----
    #pragma unroll
    for (int mt = 0; mt < 4; mt++){
        #pragma unroll
        for (int r = 0; r < 4; r++){
            const int row = th*64 + mt*16 + kg*4 + r;
            const float2 a0 = sStat[row];
            const float2 a1 = sStat[128 + row];
            const float s0 = a0.x + a1.x, s1 = a0.y + a1.y;
            const float mu = s0 * (1.0f/128.0f);
            const float rs = rsqrtf(s1 * (1.0f/128.0f) - mu*mu + 1e-5f);
            #pragma unroll
            for (int ct = 0; ct < 4; ct++){
                const int col = nh*64 + ct*16 + m;
                sH[row*136 + col] = f2bf(gelu_f((acc[mt][ct][r] - mu)*rs*sL2g[col] + sL2b[col]));
            }
        }
    }
    __syncthreads();

    // ---- phase 5: GEMM2  OUT[128x64] = H[128x128] @ W2^T ----
    f32x4 acc2[2][4];
    #pragma unroll
    for (int i=0;i<2;i++){ acc2[i][0]=z;acc2[i][1]=z;acc2[i][2]=z;acc2[i][3]=z; }

    const u16* wB2e = wB2 + e*8192;
    #pragma unroll
    for (int kk = 0; kk < 4; kk++){
        const int k0 = kk*32 + kg*8;
        short8 aF[2], bF[4];
        #pragma unroll
        for (int mt = 0; mt < 2; mt++){
            const int row = w*32 + mt*16 + m;
            aF[mt] = *(const short8*)(&sH[row*136 + k0]);
        }
        #pragma unroll
        for (int ct = 0; ct < 4; ct++)
            bF[ct] = *(const short8*)(wB2e + (ct*16 + m)*128 + k0);
        #pragma unroll
        for (int mt = 0; mt < 2; mt++)
            #pragma unroll
            for (int ct = 0; ct < 4; ct++)
                acc2[mt][ct] = __builtin_amdgcn_mfma_f32_16x16x32_bf16(aF[mt], bF[ct], acc2[mt][ct], 0,0,0);
    }

    // ---- phase 6: +b2, bf16, stage to out tile (sA1 reuse, dead since phase-3 barrier) ----
    #pragma unroll
    for (int mt = 0; mt < 2; mt++){
        #pragma unroll
        for (int r = 0; r < 4; r++){
            const int row = w*32 + mt*16 + kg*4 + r;
            #pragma unroll
            for (int ct = 0; ct < 4; ct++){
                const int col = ct*16 + m;
                sA1[row*72 + col] = f2bf(acc2[mt][ct][r] + sB2[col]);
            }
        }
    }
    __syncthreads();

    // ---- phase 7: coalesced 16B stores (block's aout rows are contiguous) ----
    #pragma unroll
    for (int it = 0; it < 4; it++){
        const int idx = it*256 + tid;          // 0..1023
        const int row = idx >> 3, qq = idx & 7;
        if (aBase + row < cnt){
            uint4 v = *(const uint4*)(&sA1[row*72 + qq*8]);
            *(uint4*)(aout + ((size_t)(off + aBase + row) << 6) + qq*8) = v;
        }
    }
}

// ---------------- kernel 5 (fallback, scalar — used only if ws too small) ----------------
__global__ __launch_bounds__(256,2) void k_expert(
    const float* __restrict__ x_src, const u32* __restrict__ bucket, const u32* __restrict__ counts,
    const float* __restrict__ W1,  const float* __restrict__ W2,
    const float* __restrict__ l1g, const float* __restrict__ l1b,
    const float* __restrict__ l2g, const float* __restrict__ l2b,
    const float* __restrict__ b2,  u16* __restrict__ aout)
{
    const int e = blockIdx.x >> 9;
    const int c = blockIdx.x & 511;
    const int cnt = (int)counts[e];
    const int aBase = c * 256;
    if (aBase >= cnt) return;

    int off = 0;
    for (int ee = 0; ee < 8; ee++){ if (ee < e) off += (int)counts[ee]; }

    __shared__ float sW1[8192];
    __shared__ float sW2T[128*68];
    __shared__ float sL1g[64], sL1b[64], sL2g[128], sL2b[128], sB2[64];
    const int tid = threadIdx.x;
    for (int i = tid; i < 8192; i += 256){
        sW1[i] = W1[e*8192 + i];
        int d = i >> 7, j = i & 127;
        sW2T[j*68 + d] = W2[e*8192 + i];
    }
    if (tid < 64){ sL1g[tid] = l1g[e*64+tid]; sL1b[tid] = l1b[e*64+tid]; sB2[tid] = b2[e*64+tid]; }
    if (tid < 128){ sL2g[tid] = l2g[e*128+tid]; sL2b[tid] = l2b[e*128+tid]; }
    __syncthreads();

    const int a = aBase + tid;
    if (a >= cnt) return;
    const u32 pos32 = bucket[off + a];

    float g[64];
    #pragma unroll
    for (int i = 0; i < 16; i++){
        float4 t = ((const float4*)(x_src + (size_t)pos32*64))[i];
        g[i*4+0]=t.x; g[i*4+1]=t.y; g[i*4+2]=t.z; g[i*4+3]=t.w;
    }

    float s0 = 0.f, s1 = 0.f;
    #pragma unroll
    for (int d = 0; d < 64; d++){ s0 += g[d]; s1 += g[d]*g[d]; }
    float m  = s0 * (1.0f/64.0f);
    float va = s1 * (1.0f/64.0f) - m*m;
    float rs = rsqrtf(va + 1e-5f);
    #pragma unroll
    for (int d = 0; d < 64; d++) g[d] = gelu_f((g[d]-m)*rs*sL1g[d] + sL1b[d]);

    u32 hpk[64];
    float hs = 0.f, hs2 = 0.f;
    for (int jp = 0; jp < 64; jp++){
        float h0, h1;
        {
            float a0=0.f,a1=0.f,a2=0.f,a3=0.f;
            const float4* w4 = (const float4*)&sW1[(2*jp)*64];
            #pragma unroll
            for (int i = 0; i < 16; i++){
                float4 ww = w4[i];
                a0 += ww.x*g[i*4+0]; a1 += ww.y*g[i*4+1]; a2 += ww.z*g[i*4+2]; a3 += ww.w*g[i*4+3];
            }
            h0 = (a0+a1)+(a2+a3);
        }
        {
            float a0=0.f,a1=0.f,a2=0.f,a3=0.f;
            const float4* w4 = (const float4*)&sW1[(2*jp+1)*64];
            #pragma unroll
            for (int i = 0; i < 16; i++){
                float4 ww = w4[i];
                a0 += ww.x*g[i*4+0]; a1 += ww.y*g[i*4+1]; a2 += ww.z*g[i*4+2]; a3 += ww.w*g[i*4+3];
            }
            h1 = (a0+a1)+(a2+a3);
        }
        hs += h0 + h1; hs2 += h0*h0 + h1*h1;
        hpk[jp] = (u32)f2bf(h0) | ((u32)f2bf(h1) << 16);
    }
    float m2  = hs  * (1.0f/128.0f);
    float va2 = hs2 * (1.0f/128.0f) - m2*m2;
    float rs2 = rsqrtf(va2 + 1e-5f);

    float acc[64];
    #pragma unroll
    for (int d = 0; d < 64; d++) acc[d] = sB2[d];
    for (int j = 0; j < 128; j++){
        float hj = bf2f((u16)((j & 1) ? (hpk[j>>1] >> 16) : (hpk[j>>1] & 0xffffu)));
        float gh = gelu_f((hj - m2)*rs2*sL2g[j] + sL2b[j]);
        const float4* w2t = (const float4*)&sW2T[j*68];
        #pragma unroll
        for (int d4 = 0; d4 < 16; d4++){
            float4 w = w2t[d4];
            acc[d4*4+0] += gh * w.x;
            acc[d4*4+1] += gh * w.y;
            acc[d4*4+2] += gh * w.z;
            acc[d4*4+3] += gh * w.w;
        }
    }

    u16* op = aout + (size_t)(off + a) * 64;
    #pragma unroll
    for (int dc = 0; dc < 8; dc++){
        uint4 o;
        o.x = (u32)f2bf(acc[dc*8+0]) | ((u32)f2bf(acc[dc*8+1]) << 16);
        o.y = (u32)f2bf(acc[dc*8+2]) | ((u32)f2bf(acc[dc*8+3]) << 16);
        o.z = (u32)f2bf(acc[dc*8+4]) | ((u32)f2bf(acc[dc*8+5]) << 16);
        o.w = (u32)f2bf(acc[dc*8+6]) | ((u32)f2bf(acc[dc*8+7]) << 16);
        ((uint4*)op)[dc] = o;
    }
}

// ---------------- kernel 6: combine top-2 expert outputs -> out0 (overwrites x) ----------------
__global__ __launch_bounds__(256,4) void k_combine(
    const u16* __restrict__ aout, const uint4* __restrict__ topiv,
    const int2* __restrict__ slots, float* __restrict__ out0)
{
    const int tid = threadIdx.x;
    const int p   = blockIdx.x*16 + (tid >> 4);
    const int cq  = tid & 15;

    const int h  = p & (NH_-1);
    const int bs = p >> 4;
    const int b  = bs >> 10, s = bs & (S_-1);
    const int n  = ((b*NH_ + h) << 10) + s;

    uint4 t = topiv[n];
    float w1 = __uint_as_float(t.z), w2 = __uint_as_float(t.w);
    int2 sl = slots[n];

    uint2 ua = *(const uint2*)(aout + (size_t)sl.x*64 + cq*4);
    uint2 ub = *(const uint2*)(aout + (size_t)sl.y*64 + cq*4);

    float4 o;
    o.x = w1*bf2f((u16)(ua.x & 0xffffu)) + w2*bf2f((u16)(ub.x & 0xffffu));
    o.y = w1*bf2f((u16)(ua.x >> 16))     + w2*bf2f((u16)(ub.x >> 16));
    o.z = w1*bf2f((u16)(ua.y & 0xffffu)) + w2*bf2f((u16)(ub.y & 0xffffu));
    o.w = w1*bf2f((u16)(ua.y >> 16))     + w2*bf2f((u16)(ub.y >> 16));
    *(float4*)(out0 + (size_t)p*64 + cq*4) = o;
}

// ---------------- launch ----------------
extern "C" void kernel_launch(void* const* d_in, const int* in_sizes, int n_in,
                              void* d_out, int out_size, void* d_ws, size_t ws_size,
                              hipStream_t stream)
{
    const float* qin = (const float*)d_in[0];
    const float* kin = (const float*)d_in[1];
    const float* vin = (const float*)d_in[2];
    const float* mem = (const float*)d_in[3];
    const float* Wq  = (const float*)d_in[4];
    const float* Wk  = (const float*)d_in[5];
    const float* Wv  = (const float*)d_in[6];
    const float* fg  = (const float*)d_in[7];
    const float* gW  = (const float*)d_in[8];
    const float* gB  = (const float*)d_in[9];
    const float* l1g = (const float*)d_in[10];
    const float* l1b = (const float*)d_in[11];
    const float* W1  = (const float*)d_in[12];
    const float* l2g = (const float*)d_in[13];
    const float* l2b = (const float*)d_in[14];
    const float* W2  = (const float*)d_in[15];
    const float* b2  = (const float*)d_in[16];

    float* out0 = (float*)d_out;                    // token_mixing [B,S,NH*HD]
    float* out1 = out0 + (size_t)NTOK * 64;         // current_memorys [B,NH,S,HD]

    // ws layout (base 37.75 MB proven; +256 KB bf16 weights, guarded by ws_size)
    char* ws = (char*)d_ws;
    u16*   aout   = (u16*)(ws);                               // 2N*64*2  = 33,554,432
    uint4* topiv  = (uint4*)(ws + (size_t)33554432);          // N*16     =  2,097,152
    int2*  slots  = (int2*)(ws + (size_t)35651584);           // N*8      =  1,048,576
    u32*   bucket = (u32*)(ws + (size_t)36700160);            // 2N*4     =  1,048,576
    u32*   counts = (u32*)(ws + (size_t)37748736);            // 16*4
    u32*   cursors = counts + 8;
    u16*   wB1    = (u16*)(ws + (size_t)37749760);            // 131072 B (bf16 W1)
    u16*   wB2    = (u16*)(ws + (size_t)37880832);            // 131072 B (bf16 W2)
    const size_t WS_NEED = 38011904;

    (void)in_sizes; (void)n_in; (void)out_size;

    const bool use_mfma = (ws_size >= WS_NEED);

    k_zero   <<<1, 64, 0, stream>>>(counts);
    if (use_mfma)
        k_prep <<<256, 256, 0, stream>>>(W1, W2, wB1, wB2);
    k_mem    <<<512, 256, 0, stream>>>(kin, vin, mem, Wk, Wv, fg, out1);
    k_q      <<<512, 256, 0, stream>>>(qin, out1, Wq, out0);
    k_gate   <<<NTOK/256, 256, 0, stream>>>(out0, gW, gB, topiv, counts);
    k_scatter<<<NTOK/256, 256, 0, stream>>>(topiv, counts, cursors, bucket, slots);
    if (use_mfma)
        k_expert_mfma<<<E_*1024, 256, 0, stream>>>(out0, bucket, counts, wB1, wB2,
                                                   l1g, l1b, l2g, l2b, b2, aout);
    else
        k_expert <<<E_*512, 256, 0, stream>>>(out0, bucket, counts, W1, W2,
                                              l1g, l1b, l2g, l2b, b2, aout);
    k_combine<<<NTOK/16, 256, 0, stream>>>(aout, topiv, slots, out0);
}

// Round 3
// 397.360 us; speedup vs baseline: 3.0145x; 2.3486x over previous
//
#include <hip/hip_runtime.h>
#include <stdint.h>

typedef unsigned short u16;
typedef unsigned int   u32;
typedef unsigned long long u64;
typedef __attribute__((ext_vector_type(8))) short short8;
typedef __attribute__((ext_vector_type(4))) short s16x4;
typedef __attribute__((ext_vector_type(4))) float f32x4;

#define B_    8
#define S_    1024
#define HID_  1024
#define NH_   16
#define HD_   64
#define E_    8
#define IDIM_ 128
#define NTOK  (B_*NH_*S_)   /* 131072 */

// padded-counter stride: one 64B cacheline per expert
#define CSTRIDE 16

// ---------- helpers ----------
__device__ __forceinline__ float bf2f(u16 u){ return __uint_as_float(((u32)u) << 16); }
__device__ __forceinline__ u16 f2bf(float f){
    u32 u = __float_as_uint(f);
    u32 r = u + 0x7fffu + ((u >> 16) & 1u);   // RNE
    return (u16)(r >> 16);
}
// 8 consecutive fp32 -> bf16 MFMA fragment (A or B operand)
__device__ __forceinline__ short8 frag8(const float* __restrict__ p){
    float4 a = *(const float4*)p;
    float4 b = *(const float4*)(p + 4);
    short8 r;
    r[0]=(short)f2bf(a.x); r[1]=(short)f2bf(a.y); r[2]=(short)f2bf(a.z); r[3]=(short)f2bf(a.w);
    r[4]=(short)f2bf(b.x); r[5]=(short)f2bf(b.y); r[6]=(short)f2bf(b.z); r[7]=(short)f2bf(b.w);
    return r;
}
__device__ __forceinline__ float gelu_f(float x){
    return 0.5f * x * (1.0f + erff(x * 0.70710678118654752f));
}

// ---------------- kernel 0: zero padded counters (counts 128 u32 + cursors 128 u32) ----------------
__global__ void k_zero(u32* c){
    c[threadIdx.x] = 0;   // launched with 256 threads
}

// ---------------- kernel 0b: fp32 weights -> bf16 (both natural layout) ----------------
__global__ __launch_bounds__(256) void k_prep(
    const float* __restrict__ W1, const float* __restrict__ W2,
    u16* __restrict__ wB1, u16* __restrict__ wB2)
{
    const int i = blockIdx.x*256 + threadIdx.x;   // grid 256 -> 65536
    wB1[i] = f2bf(W1[i]);                         // [e][j=128][d=64]
    wB2[i] = f2bf(W2[i]);                         // [e][n=64][k=128]
}

// ---------------- kernel 1: MFMA k/v projection + memory cell -> current_memorys ----------------
__global__ __launch_bounds__(256,2) void k_mem(
    const float* __restrict__ kin, const float* __restrict__ vin, const float* __restrict__ mem,
    const float* __restrict__ Wk,  const float* __restrict__ Wv,  const float* __restrict__ fg,
    float* __restrict__ cur_out)
{
    const int lane = threadIdx.x & 63;
    const int wid  = threadIdx.x >> 6;
    const int m    = lane & 15;
    const int kg   = lane >> 4;

    const int slab  = blockIdx.x;
    const int chunk = slab & 3, h = (slab >> 2) & 15, b = slab >> 6;
    const int tw    = chunk*256 + wid*64;

    const float* kbase = kin + ((size_t)b*S_)*HID_ + h*64;
    const float* vbase = vin + ((size_t)b*S_)*HID_ + h*64;

    f32x4 accK[4][4], accV[4][4];
    const f32x4 z = {0.f,0.f,0.f,0.f};
    #pragma unroll
    for (int i=0;i<4;i++){ accK[i][0]=z;accK[i][1]=z;accK[i][2]=z;accK[i][3]=z;
                           accV[i][0]=z;accV[i][1]=z;accV[i][2]=z;accV[i][3]=z; }

    #pragma unroll
    for (int kk=0; kk<2; kk++){
        const int k0 = kk*32 + kg*8;
        short8 aF[4], bF[4];
        #pragma unroll
        for (int mt=0; mt<4; mt++) aF[mt] = frag8(kbase + (size_t)(tw + mt*16 + m)*HID_ + k0);
        #pragma unroll
        for (int ct=0; ct<4; ct++) bF[ct] = frag8(Wk + (ct*16 + m)*64 + k0);
        #pragma unroll
        for (int mt=0; mt<4; mt++)
            #pragma unroll
            for (int ct=0; ct<4; ct++)
                accK[mt][ct] = __builtin_amdgcn_mfma_f32_16x16x32_bf16(aF[mt], bF[ct], accK[mt][ct], 0,0,0);
    }
    #pragma unroll
    for (int kk=0; kk<2; kk++){
        const int k0 = kk*32 + kg*8;
        short8 aF[4], bF[4];
        #pragma unroll
        for (int mt=0; mt<4; mt++) aF[mt] = frag8(vbase + (size_t)(tw + mt*16 + m)*HID_ + k0);
        #pragma unroll
        for (int ct=0; ct<4; ct++) bF[ct] = frag8(Wv + (ct*16 + m)*64 + k0);
        #pragma unroll
        for (int mt=0; mt<4; mt++)
            #pragma unroll
            for (int ct=0; ct<4; ct++)
                accV[mt][ct] = __builtin_amdgcn_mfma_f32_16x16x32_bf16(aF[mt], bF[ct], accV[mt][ct], 0,0,0);
    }

    const size_t nb = ((size_t)(b*NH_ + h)) << 10;
    float fgv[4];
    #pragma unroll
    for (int ct=0; ct<4; ct++) fgv[ct] = fg[ct*16 + m];

    #pragma unroll
    for (int mt=0; mt<4; mt++){
        #pragma unroll
        for (int r=0; r<4; r++){
            const int tok = tw + mt*16 + kg*4 + r;
            const size_t rowo = (nb + (size_t)tok)*64;
            #pragma unroll
            for (int ct=0; ct<4; ct++){
                const int d = ct*16 + m;
                const float kd = accK[mt][ct][r];
                const float vd = accV[mt][ct][r];
                const float f  = fgv[ct];
                const float mv = mem[rowo + d];
                const float cell = kd*vd + f*mv;
                cur_out[rowo + d] = (1.0f - f)*cell + f*mv;
            }
        }
    }
}

// ---------------- kernel 2: MFMA q projection; x = q_*cur -> out0 at final pos ----------------
__global__ __launch_bounds__(256,2) void k_q(
    const float* __restrict__ qin, const float* __restrict__ cur_in, const float* __restrict__ Wq,
    float* __restrict__ out0)
{
    const int lane = threadIdx.x & 63;
    const int wid  = threadIdx.x >> 6;
    const int m    = lane & 15;
    const int kg   = lane >> 4;

    const int slab  = blockIdx.x;
    const int chunk = slab & 3, h = (slab >> 2) & 15, b = slab >> 6;
    const int tw    = chunk*256 + wid*64;

    const float* qbase = qin + ((size_t)b*S_)*HID_ + h*64;

    f32x4 accQ[4][4];
    const f32x4 z = {0.f,0.f,0.f,0.f};
    #pragma unroll
    for (int i=0;i<4;i++){ accQ[i][0]=z;accQ[i][1]=z;accQ[i][2]=z;accQ[i][3]=z; }

    #pragma unroll
    for (int kk=0; kk<2; kk++){
        const int k0 = kk*32 + kg*8;
        short8 aF[4], bF[4];
        #pragma unroll
        for (int mt=0; mt<4; mt++) aF[mt] = frag8(qbase + (size_t)(tw + mt*16 + m)*HID_ + k0);
        #pragma unroll
        for (int ct=0; ct<4; ct++) bF[ct] = frag8(Wq + (ct*16 + m)*64 + k0);
        #pragma unroll
        for (int mt=0; mt<4; mt++)
            #pragma unroll
            for (int ct=0; ct<4; ct++)
                accQ[mt][ct] = __builtin_amdgcn_mfma_f32_16x16x32_bf16(aF[mt], bF[ct], accQ[mt][ct], 0,0,0);
    }

    const size_t nb = ((size_t)(b*NH_ + h)) << 10;
    #pragma unroll
    for (int mt=0; mt<4; mt++){
        #pragma unroll
        for (int r=0; r<4; r++){
            const int tok = tw + mt*16 + kg*4 + r;
            const size_t curo = (nb + (size_t)tok)*64;
            const size_t po   = ((size_t)(b*S_ + tok)*NH_ + h)*64;
            #pragma unroll
            for (int ct=0; ct<4; ct++){
                const int d = ct*16 + m;
                out0[po + d] = accQ[mt][ct][r] * cur_in[curo + d];
            }
        }
    }
}

// ---------------- kernel 3: gate logits + top-2 (block-aggregated counts) ----------------
__global__ __launch_bounds__(256,2) void k_gate(
    const float* __restrict__ x_src, const float* __restrict__ gW, const float* __restrict__ gB,
    uint4* __restrict__ topiv, u32* __restrict__ counts)
{
    __shared__ float sGW[512], sGB[8];
    __shared__ u32 sWc[4][8];
    const int tid = threadIdx.x;
    for (int i = tid; i < 512; i += 256) sGW[i] = gW[i];
    if (tid < 8) sGB[tid] = gB[tid];
    __syncthreads();

    const int n = blockIdx.x*256 + tid;
    const int s = n & (S_-1), h = (n >> 10) & (NH_-1), b = n >> 14;
    const size_t po = ((size_t)(b*S_ + s)*NH_ + h)*64;

    float lg[8];
    #pragma unroll
    for (int e = 0; e < 8; e++) lg[e] = sGB[e];

    for (int dc = 0; dc < 16; dc++){
        float4 x4 = ((const float4*)(x_src + po))[dc];
        float xv[4] = {x4.x, x4.y, x4.z, x4.w};
        #pragma unroll
        for (int i = 0; i < 4; i++){
            const int d = dc*4 + i;
            #pragma unroll
            for (int e = 0; e < 8; e++) lg[e] += sGW[e*64 + d] * xv[i];
        }
    }

    int i1 = 0; float v1 = lg[0];
    #pragma unroll
    for (int e = 1; e < 8; e++){ if (lg[e] > v1){ v1 = lg[e]; i1 = e; } }
    int i2 = -1; float v2 = -3.0e38f;
    #pragma unroll
    for (int e = 0; e < 8; e++){ if (e != i1 && lg[e] > v2){ v2 = lg[e]; i2 = e; } }

    topiv[n] = make_uint4((u32)i1, (u32)i2, __float_as_uint(v1), __float_as_uint(v2));

    const int lane = tid & 63;
    const int w    = tid >> 6;
    #pragma unroll
    for (int e = 0; e < 8; e++){
        u64 m1 = __ballot(i1 == e);
        u64 m2 = __ballot(i2 == e);
        if (lane == 0) sWc[w][e] = (u32)(__popcll(m1) + __popcll(m2));
    }
    __syncthreads();
    if (tid < 8){
        u32 t = sWc[0][tid] + sWc[1][tid] + sWc[2][tid] + sWc[3][tid];
        if (t) atomicAdd(&counts[tid*CSTRIDE], t);
    }
}

// ---------------- kernel 4: scatter into compact per-expert lists (block-aggregated atomics) ----------------
__global__ __launch_bounds__(256,2) void k_scatter(
    const uint4* __restrict__ topiv, const u32* __restrict__ counts, u32* __restrict__ cursors,
    u32* __restrict__ bucket, int2* __restrict__ slots)
{
    __shared__ u32 sC1[4][8], sC2[4][8];   // per-wave counts
    __shared__ u32 sB1[4][8], sB2[4][8];   // per-wave global bases

    const int tid = threadIdx.x;
    const int n = blockIdx.x*256 + tid;
    uint4 t = topiv[n];
    const int i1 = (int)t.x, i2 = (int)t.y;

    int off[8]; int acc = 0;
    #pragma unroll
    for (int e = 0; e < 8; e++){ off[e] = acc; acc += (int)counts[e*CSTRIDE]; }

    const int s = n & (S_-1), h = (n >> 10) & (NH_-1), b = n >> 14;
    const u32 pos32 = (u32)((b*S_ + s)*NH_ + h);

    const int lane = tid & 63;
    const int w    = tid >> 6;
    const u64 low = (1ull << lane) - 1ull;

    u64 myM1 = 0, myM2 = 0;
    #pragma unroll
    for (int e = 0; e < 8; e++){
        u64 m1 = __ballot(i1 == e);
        u64 m2 = __ballot(i2 == e);
        if (i1 == e) myM1 = m1;
        if (i2 == e) myM2 = m2;
        if (lane == 0){ sC1[w][e] = (u32)__popcll(m1); sC2[w][e] = (u32)__popcll(m2); }
    }
    __syncthreads();

    if (tid < 8){
        const int e = tid;
        u32 tot = 0;
        #pragma unroll
        for (int ww = 0; ww < 4; ww++) tot += sC1[ww][e] + sC2[ww][e];
        u32 base = tot ? atomicAdd(&cursors[e*CSTRIDE], tot) : 0;
        u32 run = base;
        #pragma unroll
        for (int ww = 0; ww < 4; ww++){
            sB1[ww][e] = run; run += sC1[ww][e];
            sB2[ww][e] = run; run += sC2[ww][e];
        }
    }
    __syncthreads();

    const int slot1 = off[i1] + (int)sB1[w][i1] + (int)__popcll(myM1 & low);
    const int slot2 = off[i2] + (int)sB2[w][i2] + (int)__popcll(myM2 & low);

    bucket[slot1] = pos32;
    bucket[slot2] = pos32;
    slots[n] = make_int2(slot1, slot2);
}

// ---------------- kernel 5 (MFMA): compacted expert FFN — simple padded-stride layout ----------------
__global__ __launch_bounds__(256,2) void k_expert_mfma(
    const float* __restrict__ x_src, const u32* __restrict__ bucket, const u32* __restrict__ counts,
    const u16* __restrict__ wB1, const u16* __restrict__ wB2,
    const float* __restrict__ l1g, const float* __restrict__ l1b,
    const float* __restrict__ l2g, const float* __restrict__ l2b,
    const float* __restrict__ b2,  u16* __restrict__ aout)
{
    const int e = blockIdx.x >> 10;
    const int c = blockIdx.x & 1023;
    const int cnt = (int)counts[e*CSTRIDE];
    const int aBase = c * 128;
    if (aBase >= cnt) return;     // block-uniform, before any barrier

    int off = 0;
    #pragma unroll
    for (int ee = 0; ee < 8; ee++){ if (ee < e) off += (int)counts[ee*CSTRIDE]; }

    __shared__ __align__(16) u16 sA1[128*72];    // gelu(LN1(x)) bf16; reused as out tile
    __shared__ __align__(16) u16 sH [128*136];   // gelu(LN2(H)) bf16
    __shared__ float2 sStat[2*128];              // per-row partial {sum,sumsq} per n-half
    __shared__ u32   sPos[128];
    __shared__ float sL1g[64], sL1b[64], sL2g[128], sL2b[128], sB2[64];

    const int tid = threadIdx.x;
    if (tid < 64){ sL1g[tid] = l1g[e*64+tid]; sL1b[tid] = l1b[e*64+tid]; sB2[tid] = b2[e*64+tid]; }
    else if (tid < 192){ int t = tid - 64; sL2g[t] = l2g[e*128+t]; sL2b[t] = l2b[e*128+t]; }
    if (tid < 128){
        int a = aBase + tid; if (a > cnt-1) a = cnt-1;   // clamp tail: duplicate last token
        sPos[tid] = bucket[off + a];
    }
    __syncthreads();

    // ---- phase 1: gather x, LN1, gelu, stage bf16 (16 lanes per token) ----
    {
        const int q = tid & 15;
        #pragma unroll
        for (int it = 0; it < 8; it++){
            const int tok = it*16 + (tid >> 4);
            const u32 pos = sPos[tok];
            float4 x4 = *(const float4*)(x_src + ((size_t)pos << 6) + q*4);
            float s0 = x4.x + x4.y + x4.z + x4.w;
            float s1 = x4.x*x4.x + x4.y*x4.y + x4.z*x4.z + x4.w*x4.w;
            #pragma unroll
            for (int msk = 1; msk < 16; msk <<= 1){
                s0 += __shfl_xor(s0, msk);
                s1 += __shfl_xor(s1, msk);
            }
            const float mu = s0 * (1.0f/64.0f);
            const float rs = rsqrtf(s1 * (1.0f/64.0f) - mu*mu + 1e-5f);
            s16x4 pk;
            pk[0] = (short)f2bf(gelu_f((x4.x - mu)*rs*sL1g[q*4+0] + sL1b[q*4+0]));
            pk[1] = (short)f2bf(gelu_f((x4.y - mu)*rs*sL1g[q*4+1] + sL1b[q*4+1]));
            pk[2] = (short)f2bf(gelu_f((x4.z - mu)*rs*sL1g[q*4+2] + sL1b[q*4+2]));
            pk[3] = (short)f2bf(gelu_f((x4.w - mu)*rs*sL1g[q*4+3] + sL1b[q*4+3]));
            *(s16x4*)(&sA1[tok*72 + q*4]) = pk;
        }
    }
    __syncthreads();

    // ---- phase 2: GEMM1  H[128x128] = A1[128x64] @ W1^T ----
    const int lane = tid & 63;
    const int w    = tid >> 6;
    const int m    = lane & 15;
    const int kg   = lane >> 4;
    const int th   = w >> 1;        // token half (64 rows)
    const int nh   = w & 1;         // n half (64 cols)

    f32x4 acc[4][4];
    const f32x4 z = {0.f,0.f,0.f,0.f};
    #pragma unroll
    for (int i=0;i<4;i++){ acc[i][0]=z;acc[i][1]=z;acc[i][2]=z;acc[i][3]=z; }

    const u16* wB1e = wB1 + e*8192;
    #pragma unroll
    for (int kk = 0; kk < 2; kk++){
        const int k0 = kk*32 + kg*8;
        short8 aF[4], bF[4];
        #pragma unroll
        for (int mt = 0; mt < 4; mt++){
            const int row = th*64 + mt*16 + m;
            aF[mt] = *(const short8*)(&sA1[row*72 + k0]);
        }
        #pragma unroll
        for (int ct = 0; ct < 4; ct++)
            bF[ct] = *(const short8*)(wB1e + (nh*64 + ct*16 + m)*64 + k0);
        #pragma unroll
        for (int mt = 0; mt < 4; mt++)
            #pragma unroll
            for (int ct = 0; ct < 4; ct++)
                acc[mt][ct] = __builtin_amdgcn_mfma_f32_16x16x32_bf16(aF[mt], bF[ct], acc[mt][ct], 0,0,0);
    }

    // ---- phase 3: LN2 stats — per-row partials over this wave's 64 cols ----
    #pragma unroll
    for (int mt = 0; mt < 4; mt++){
        #pragma unroll
        for (int r = 0; r < 4; r++){
            float v0 = acc[mt][0][r], v1 = acc[mt][1][r], v2 = acc[mt][2][r], v3 = acc[mt][3][r];
            float p0 = (v0+v1)+(v2+v3);
            float p1 = (v0*v0+v1*v1)+(v2*v2+v3*v3);
            #pragma unroll
            for (int msk = 1; msk < 16; msk <<= 1){
                p0 += __shfl_xor(p0, msk);
                p1 += __shfl_xor(p1, msk);
            }
            if (m == 0){
                const int row = th*64 + mt*16 + kg*4 + r;
                sStat[nh*128 + row] = make_float2(p0, p1);
            }
        }
    }
    __syncthreads();

    // ---- phase 4: gelu(LN2(H)) -> sH bf16 (scalar stores, logical col order) ----
    #pragma unroll
    for (int mt = 0; mt < 4; mt++){
        #pragma unroll
        for (int r = 0; r < 4; r++){
            const int row = th*64 + mt*16 + kg*4 + r;
            const float2 a0 = sStat[row];
            const float2 a1 = sStat[128 + row];
            const float s0 = a0.x + a1.x, s1 = a0.y + a1.y;
            const float mu = s0 * (1.0f/128.0f);
            const float rs = rsqrtf(s1 * (1.0f/128.0f) - mu*mu + 1e-5f);
            #pragma unroll
            for (int ct = 0; ct < 4; ct++){
                const int col = nh*64 + ct*16 + m;
                sH[row*136 + col] = f2bf(gelu_f((acc[mt][ct][r] - mu)*rs*sL2g[col] + sL2b[col]));
            }
        }
    }
    __syncthreads();

    // ---- phase 5: GEMM2  OUT[128x64] = H[128x128] @ W2^T ----
    f32x4 acc2[2][4];
    #pragma unroll
    for (int i=0;i<2;i++){ acc2[i][0]=z;acc2[i][1]=z;acc2[i][2]=z;acc2[i][3]=z; }

    const u16* wB2e = wB2 + e*8192;
    #pragma unroll
    for (int kk = 0; kk < 4; kk++){
        const int k0 = kk*32 + kg*8;
        short8 aF[2], bF[4];
        #pragma unroll
        for (int mt = 0; mt < 2; mt++){
            const int row = w*32 + mt*16 + m;
            aF[mt] = *(const short8*)(&sH[row*136 + k0]);
        }
        #pragma unroll
        for (int ct = 0; ct < 4; ct++)
            bF[ct] = *(const short8*)(wB2e + (ct*16 + m)*128 + k0);
        #pragma unroll
        for (int mt = 0; mt < 2; mt++)
            #pragma unroll
            for (int ct = 0; ct < 4; ct++)
                acc2[mt][ct] = __builtin_amdgcn_mfma_f32_16x16x32_bf16(aF[mt], bF[ct], acc2[mt][ct], 0,0,0);
    }

    // ---- phase 6: +b2, bf16, stage to out tile (sA1 reuse, dead since phase-3 barrier) ----
    #pragma unroll
    for (int mt = 0; mt < 2; mt++){
        #pragma unroll
        for (int r = 0; r < 4; r++){
            const int row = w*32 + mt*16 + kg*4 + r;
            #pragma unroll
            for (int ct = 0; ct < 4; ct++){
                const int col = ct*16 + m;
                sA1[row*72 + col] = f2bf(acc2[mt][ct][r] + sB2[col]);
            }
        }
    }
    __syncthreads();

    // ---- phase 7: coalesced 16B stores (block's aout rows are contiguous) ----
    #pragma unroll
    for (int it = 0; it < 4; it++){
        const int idx = it*256 + tid;          // 0..1023
        const int row = idx >> 3, qq = idx & 7;
        if (aBase + row < cnt){
            uint4 v = *(const uint4*)(&sA1[row*72 + qq*8]);
            *(uint4*)(aout + ((size_t)(off + aBase + row) << 6) + qq*8) = v;
        }
    }
}

// ---------------- kernel 5 (fallback, scalar — used only if ws too small) ----------------
__global__ __launch_bounds__(256,2) void k_expert(
    const float* __restrict__ x_src, const u32* __restrict__ bucket, const u32* __restrict__ counts,
    const float* __restrict__ W1,  const float* __restrict__ W2,
    const float* __restrict__ l1g, const float* __restrict__ l1b,
    const float* __restrict__ l2g, const float* __restrict__ l2b,
    const float* __restrict__ b2,  u16* __restrict__ aout)
{
    const int e = blockIdx.x >> 9;
    const int c = blockIdx.x & 511;
    const int cnt = (int)counts[e*CSTRIDE];
    const int aBase = c * 256;
    if (aBase >= cnt) return;

    int off = 0;
    for (int ee = 0; ee < 8; ee++){ if (ee < e) off += (int)counts[ee*CSTRIDE]; }

    __shared__ float sW1[8192];
    __shared__ float sW2T[128*68];
    __shared__ float sL1g[64], sL1b[64], sL2g[128], sL2b[128], sB2[64];
    const int tid = threadIdx.x;
    for (int i = tid; i < 8192; i += 256){
        sW1[i] = W1[e*8192 + i];
        int d = i >> 7, j = i & 127;
        sW2T[j*68 + d] = W2[e*8192 + i];
    }
    if (tid < 64){ sL1g[tid] = l1g[e*64+tid]; sL1b[tid] = l1b[e*64+tid]; sB2[tid] = b2[e*64+tid]; }
    if (tid < 128){ sL2g[tid] = l2g[e*128+tid]; sL2b[tid] = l2b[e*128+tid]; }
    __syncthreads();

    const int a = aBase + tid;
    if (a >= cnt) return;
    const u32 pos32 = bucket[off + a];

    float g[64];
    #pragma unroll
    for (int i = 0; i < 16; i++){
        float4 t = ((const float4*)(x_src + (size_t)pos32*64))[i];
        g[i*4+0]=t.x; g[i*4+1]=t.y; g[i*4+2]=t.z; g[i*4+3]=t.w;
    }

    float s0 = 0.f, s1 = 0.f;
    #pragma unroll
    for (int d = 0; d < 64; d++){ s0 += g[d]; s1 += g[d]*g[d]; }
    float m  = s0 * (1.0f/64.0f);
    float va = s1 * (1.0f/64.0f) - m*m;
    float rs = rsqrtf(va + 1e-5f);
    #pragma unroll
    for (int d = 0; d < 64; d++) g[d] = gelu_f((g[d]-m)*rs*sL1g[d] + sL1b[d]);

    u32 hpk[64];
    float hs = 0.f, hs2 = 0.f;
    for (int jp = 0; jp < 64; jp++){
        float h0, h1;
        {
            float a0=0.f,a1=0.f,a2=0.f,a3=0.f;
            const float4* w4 = (const float4*)&sW1[(2*jp)*64];
            #pragma unroll
            for (int i = 0; i < 16; i++){
                float4 ww = w4[i];
                a0 += ww.x*g[i*4+0]; a1 += ww.y*g[i*4+1]; a2 += ww.z*g[i*4+2]; a3 += ww.w*g[i*4+3];
            }
            h0 = (a0+a1)+(a2+a3);
        }
        {
            float a0=0.f,a1=0.f,a2=0.f,a3=0.f;
            const float4* w4 = (const float4*)&sW1[(2*jp+1)*64];
            #pragma unroll
            for (int i = 0; i < 16; i++){
                float4 ww = w4[i];
                a0 += ww.x*g[i*4+0]; a1 += ww.y*g[i*4+1]; a2 += ww.z*g[i*4+2]; a3 += ww.w*g[i*4+3];
            }
            h1 = (a0+a1)+(a2+a3);
        }
        hs += h0 + h1; hs2 += h0*h0 + h1*h1;
        hpk[jp] = (u32)f2bf(h0) | ((u32)f2bf(h1) << 16);
    }
    float m2  = hs  * (1.0f/128.0f);
    float va2 = hs2 * (1.0f/128.0f) - m2*m2;
    float rs2 = rsqrtf(va2 + 1e-5f);

    float acc[64];
    #pragma unroll
    for (int d = 0; d < 64; d++) acc[d] = sB2[d];
    for (int j = 0; j < 128; j++){
        float hj = bf2f((u16)((j & 1) ? (hpk[j>>1] >> 16) : (hpk[j>>1] & 0xffffu)));
        float gh = gelu_f((hj - m2)*rs2*sL2g[j] + sL2b[j]);
        const float4* w2t = (const float4*)&sW2T[j*68];
        #pragma unroll
        for (int d4 = 0; d4 < 16; d4++){
            float4 w = w2t[d4];
            acc[d4*4+0] += gh * w.x;
            acc[d4*4+1] += gh * w.y;
            acc[d4*4+2] += gh * w.z;
            acc[d4*4+3] += gh * w.w;
        }
    }

    u16* op = aout + (size_t)(off + a) * 64;
    #pragma unroll
    for (int dc = 0; dc < 8; dc++){
        uint4 o;
        o.x = (u32)f2bf(acc[dc*8+0]) | ((u32)f2bf(acc[dc*8+1]) << 16);
        o.y = (u32)f2bf(acc[dc*8+2]) | ((u32)f2bf(acc[dc*8+3]) << 16);
        o.z = (u32)f2bf(acc[dc*8+4]) | ((u32)f2bf(acc[dc*8+5]) << 16);
        o.w = (u32)f2bf(acc[dc*8+6]) | ((u32)f2bf(acc[dc*8+7]) << 16);
        ((uint4*)op)[dc] = o;
    }
}

// ---------------- kernel 6: combine top-2 expert outputs -> out0 (overwrites x) ----------------
__global__ __launch_bounds__(256,4) void k_combine(
    const u16* __restrict__ aout, const uint4* __restrict__ topiv,
    const int2* __restrict__ slots, float* __restrict__ out0)
{
    const int tid = threadIdx.x;
    const int p   = blockIdx.x*16 + (tid >> 4);
    const int cq  = tid & 15;

    const int h  = p & (NH_-1);
    const int bs = p >> 4;
    const int b  = bs >> 10, s = bs & (S_-1);
    const int n  = ((b*NH_ + h) << 10) + s;

    uint4 t = topiv[n];
    float w1 = __uint_as_float(t.z), w2 = __uint_as_float(t.w);
    int2 sl = slots[n];

    uint2 ua = *(const uint2*)(aout + (size_t)sl.x*64 + cq*4);
    uint2 ub = *(const uint2*)(aout + (size_t)sl.y*64 + cq*4);

    float4 o;
    o.x = w1*bf2f((u16)(ua.x & 0xffffu)) + w2*bf2f((u16)(ub.x & 0xffffu));
    o.y = w1*bf2f((u16)(ua.x >> 16))     + w2*bf2f((u16)(ub.x >> 16));
    o.z = w1*bf2f((u16)(ua.y & 0xffffu)) + w2*bf2f((u16)(ub.y & 0xffffu));
    o.w = w1*bf2f((u16)(ua.y >> 16))     + w2*bf2f((u16)(ub.y >> 16));
    *(float4*)(out0 + (size_t)p*64 + cq*4) = o;
}

// ---------------- launch ----------------
extern "C" void kernel_launch(void* const* d_in, const int* in_sizes, int n_in,
                              void* d_out, int out_size, void* d_ws, size_t ws_size,
                              hipStream_t stream)
{
    const float* qin = (const float*)d_in[0];
    const float* kin = (const float*)d_in[1];
    const float* vin = (const float*)d_in[2];
    const float* mem = (const float*)d_in[3];
    const float* Wq  = (const float*)d_in[4];
    const float* Wk  = (const float*)d_in[5];
    const float* Wv  = (const float*)d_in[6];
    const float* fg  = (const float*)d_in[7];
    const float* gW  = (const float*)d_in[8];
    const float* gB  = (const float*)d_in[9];
    const float* l1g = (const float*)d_in[10];
    const float* l1b = (const float*)d_in[11];
    const float* W1  = (const float*)d_in[12];
    const float* l2g = (const float*)d_in[13];
    const float* l2b = (const float*)d_in[14];
    const float* W2  = (const float*)d_in[15];
    const float* b2  = (const float*)d_in[16];

    float* out0 = (float*)d_out;                    // token_mixing [B,S,NH*HD]
    float* out1 = out0 + (size_t)NTOK * 64;         // current_memorys [B,NH,S,HD]

    // ws layout (base 37.75 MB proven; padded counters live in the 1KB gap before wB1)
    char* ws = (char*)d_ws;
    u16*   aout   = (u16*)(ws);                               // 2N*64*2  = 33,554,432
    uint4* topiv  = (uint4*)(ws + (size_t)33554432);          // N*16     =  2,097,152
    int2*  slots  = (int2*)(ws + (size_t)35651584);           // N*8      =  1,048,576
    u32*   bucket = (u32*)(ws + (size_t)36700160);            // 2N*4     =  1,048,576
    u32*   counts = (u32*)(ws + (size_t)37748736);            // 8 * 64B padded = 512B
    u32*   cursors = (u32*)(ws + (size_t)37749248);           // 8 * 64B padded = 512B
    u16*   wB1    = (u16*)(ws + (size_t)37749760);            // 131072 B (bf16 W1)
    u16*   wB2    = (u16*)(ws + (size_t)37880832);            // 131072 B (bf16 W2)
    const size_t WS_NEED = 38011904;

    (void)in_sizes; (void)n_in; (void)out_size;

    const bool use_mfma = (ws_size >= WS_NEED);

    k_zero   <<<1, 256, 0, stream>>>(counts);   // zeroes counts + cursors (256 u32 contiguous)
    if (use_mfma)
        k_prep <<<256, 256, 0, stream>>>(W1, W2, wB1, wB2);
    k_mem    <<<512, 256, 0, stream>>>(kin, vin, mem, Wk, Wv, fg, out1);
    k_q      <<<512, 256, 0, stream>>>(qin, out1, Wq, out0);
    k_gate   <<<NTOK/256, 256, 0, stream>>>(out0, gW, gB, topiv, counts);
    k_scatter<<<NTOK/256, 256, 0, stream>>>(topiv, counts, cursors, bucket, slots);
    if (use_mfma)
        k_expert_mfma<<<E_*1024, 256, 0, stream>>>(out0, bucket, counts, wB1, wB2,
                                                   l1g, l1b, l2g, l2b, b2, aout);
    else
        k_expert <<<E_*512, 256, 0, stream>>>(out0, bucket, counts, W1, W2,
                                              l1g, l1b, l2g, l2b, b2, aout);
    k_combine<<<NTOK/16, 256, 0, stream>>>(aout, topiv, slots, out0);
}

// Round 4
// 339.710 us; speedup vs baseline: 3.5261x; 1.1697x over previous
//
#include <hip/hip_runtime.h>
#include <stdint.h>

typedef unsigned short u16;
typedef unsigned int   u32;
typedef unsigned long long u64;
typedef __attribute__((ext_vector_type(8))) short short8;
typedef __attribute__((ext_vector_type(4))) short s16x4;
typedef __attribute__((ext_vector_type(4))) float f32x4;

#define B_    8
#define S_    1024
#define HID_  1024
#define NH_   16
#define HD_   64
#define E_    8
#define IDIM_ 128
#define NTOK  (B_*NH_*S_)   /* 131072 */

// padded-counter stride: one 64B cacheline per expert
#define CSTRIDE 16

// ---------- helpers ----------
__device__ __forceinline__ float bf2f(u16 u){ return __uint_as_float(((u32)u) << 16); }
__device__ __forceinline__ u16 f2bf(float f){
    u32 u = __float_as_uint(f);
    u32 r = u + 0x7fffu + ((u >> 16) & 1u);   // RNE
    return (u16)(r >> 16);
}
// 8 consecutive fp32 -> bf16 MFMA fragment (A or B operand)
__device__ __forceinline__ short8 frag8(const float* __restrict__ p){
    float4 a = *(const float4*)p;
    float4 b = *(const float4*)(p + 4);
    short8 r;
    r[0]=(short)f2bf(a.x); r[1]=(short)f2bf(a.y); r[2]=(short)f2bf(a.z); r[3]=(short)f2bf(a.w);
    r[4]=(short)f2bf(b.x); r[5]=(short)f2bf(b.y); r[6]=(short)f2bf(b.z); r[7]=(short)f2bf(b.w);
    return r;
}
// exact gelu (kept for scalar fallback path)
__device__ __forceinline__ float gelu_exact(float x){
    return 0.5f * x * (1.0f + erff(x * 0.70710678118654752f));
}
// tanh-form gelu: max abs err ~3e-4 vs exact; short dep chain, uses v_exp_f32
__device__ __forceinline__ float gelu_f(float x){
    float z = 1.5957691216057308f * (x + 0.044715f * x * x * x);   // 2*sqrt(2/pi)*(...)
    float e = __expf(z);                                            // exp(2*z_tanh)
    float t = 1.0f - 2.0f / (e + 1.0f);                             // tanh(z/... )
    return 0.5f * x * (1.0f + t);
}

// ---------------- kernel 0: zero padded counters (counts 128 u32 + cursors 128 u32) ----------------
__global__ void k_zero(u32* c){
    c[threadIdx.x] = 0;   // launched with 256 threads
}

// ---------------- kernel 0b: fp32 weights -> bf16 (both natural layout) ----------------
__global__ __launch_bounds__(256) void k_prep(
    const float* __restrict__ W1, const float* __restrict__ W2,
    u16* __restrict__ wB1, u16* __restrict__ wB2)
{
    const int i = blockIdx.x*256 + threadIdx.x;   // grid 256 -> 65536
    wB1[i] = f2bf(W1[i]);                         // [e][j=128][d=64]
    wB2[i] = f2bf(W2[i]);                         // [e][n=64][k=128]
}

// ---------------- kernel 1: MFMA k/v projection + memory cell -> current_memorys ----------------
__global__ __launch_bounds__(256,2) void k_mem(
    const float* __restrict__ kin, const float* __restrict__ vin, const float* __restrict__ mem,
    const float* __restrict__ Wk,  const float* __restrict__ Wv,  const float* __restrict__ fg,
    float* __restrict__ cur_out)
{
    const int lane = threadIdx.x & 63;
    const int wid  = threadIdx.x >> 6;
    const int m    = lane & 15;
    const int kg   = lane >> 4;

    const int slab  = blockIdx.x;
    const int chunk = slab & 3, h = (slab >> 2) & 15, b = slab >> 6;
    const int tw    = chunk*256 + wid*64;

    const float* kbase = kin + ((size_t)b*S_)*HID_ + h*64;
    const float* vbase = vin + ((size_t)b*S_)*HID_ + h*64;

    f32x4 accK[4][4], accV[4][4];
    const f32x4 z = {0.f,0.f,0.f,0.f};
    #pragma unroll
    for (int i=0;i<4;i++){ accK[i][0]=z;accK[i][1]=z;accK[i][2]=z;accK[i][3]=z;
                           accV[i][0]=z;accV[i][1]=z;accV[i][2]=z;accV[i][3]=z; }

    #pragma unroll
    for (int kk=0; kk<2; kk++){
        const int k0 = kk*32 + kg*8;
        short8 aF[4], bF[4];
        #pragma unroll
        for (int mt=0; mt<4; mt++) aF[mt] = frag8(kbase + (size_t)(tw + mt*16 + m)*HID_ + k0);
        #pragma unroll
        for (int ct=0; ct<4; ct++) bF[ct] = frag8(Wk + (ct*16 + m)*64 + k0);
        #pragma unroll
        for (int mt=0; mt<4; mt++)
            #pragma unroll
            for (int ct=0; ct<4; ct++)
                accK[mt][ct] = __builtin_amdgcn_mfma_f32_16x16x32_bf16(aF[mt], bF[ct], accK[mt][ct], 0,0,0);
    }
    #pragma unroll
    for (int kk=0; kk<2; kk++){
        const int k0 = kk*32 + kg*8;
        short8 aF[4], bF[4];
        #pragma unroll
        for (int mt=0; mt<4; mt++) aF[mt] = frag8(vbase + (size_t)(tw + mt*16 + m)*HID_ + k0);
        #pragma unroll
        for (int ct=0; ct<4; ct++) bF[ct] = frag8(Wv + (ct*16 + m)*64 + k0);
        #pragma unroll
        for (int mt=0; mt<4; mt++)
            #pragma unroll
            for (int ct=0; ct<4; ct++)
                accV[mt][ct] = __builtin_amdgcn_mfma_f32_16x16x32_bf16(aF[mt], bF[ct], accV[mt][ct], 0,0,0);
    }

    const size_t nb = ((size_t)(b*NH_ + h)) << 10;
    float fgv[4];
    #pragma unroll
    for (int ct=0; ct<4; ct++) fgv[ct] = fg[ct*16 + m];

    #pragma unroll
    for (int mt=0; mt<4; mt++){
        #pragma unroll
        for (int r=0; r<4; r++){
            const int tok = tw + mt*16 + kg*4 + r;
            const size_t rowo = (nb + (size_t)tok)*64;
            #pragma unroll
            for (int ct=0; ct<4; ct++){
                const int d = ct*16 + m;
                const float kd = accK[mt][ct][r];
                const float vd = accV[mt][ct][r];
                const float f  = fgv[ct];
                const float mv = mem[rowo + d];
                const float cell = kd*vd + f*mv;
                cur_out[rowo + d] = (1.0f - f)*cell + f*mv;
            }
        }
    }
}

// ---------------- kernel 2: MFMA q projection; x = q_*cur -> out0 at final pos ----------------
__global__ __launch_bounds__(256,2) void k_q(
    const float* __restrict__ qin, const float* __restrict__ cur_in, const float* __restrict__ Wq,
    float* __restrict__ out0)
{
    const int lane = threadIdx.x & 63;
    const int wid  = threadIdx.x >> 6;
    const int m    = lane & 15;
    const int kg   = lane >> 4;

    const int slab  = blockIdx.x;
    const int chunk = slab & 3, h = (slab >> 2) & 15, b = slab >> 6;
    const int tw    = chunk*256 + wid*64;

    const float* qbase = qin + ((size_t)b*S_)*HID_ + h*64;

    f32x4 accQ[4][4];
    const f32x4 z = {0.f,0.f,0.f,0.f};
    #pragma unroll
    for (int i=0;i<4;i++){ accQ[i][0]=z;accQ[i][1]=z;accQ[i][2]=z;accQ[i][3]=z; }

    #pragma unroll
    for (int kk=0; kk<2; kk++){
        const int k0 = kk*32 + kg*8;
        short8 aF[4], bF[4];
        #pragma unroll
        for (int mt=0; mt<4; mt++) aF[mt] = frag8(qbase + (size_t)(tw + mt*16 + m)*HID_ + k0);
        #pragma unroll
        for (int ct=0; ct<4; ct++) bF[ct] = frag8(Wq + (ct*16 + m)*64 + k0);
        #pragma unroll
        for (int mt=0; mt<4; mt++)
            #pragma unroll
            for (int ct=0; ct<4; ct++)
                accQ[mt][ct] = __builtin_amdgcn_mfma_f32_16x16x32_bf16(aF[mt], bF[ct], accQ[mt][ct], 0,0,0);
    }

    const size_t nb = ((size_t)(b*NH_ + h)) << 10;
    #pragma unroll
    for (int mt=0; mt<4; mt++){
        #pragma unroll
        for (int r=0; r<4; r++){
            const int tok = tw + mt*16 + kg*4 + r;
            const size_t curo = (nb + (size_t)tok)*64;
            const size_t po   = ((size_t)(b*S_ + tok)*NH_ + h)*64;
            #pragma unroll
            for (int ct=0; ct<4; ct++){
                const int d = ct*16 + m;
                out0[po + d] = accQ[mt][ct][r] * cur_in[curo + d];
            }
        }
    }
}

// ---------------- kernel 3: gate logits + top-2 (block-aggregated counts) ----------------
__global__ __launch_bounds__(256,2) void k_gate(
    const float* __restrict__ x_src, const float* __restrict__ gW, const float* __restrict__ gB,
    uint4* __restrict__ topiv, u32* __restrict__ counts)
{
    __shared__ float sGW[512], sGB[8];
    __shared__ u32 sWc[4][8];
    const int tid = threadIdx.x;
    for (int i = tid; i < 512; i += 256) sGW[i] = gW[i];
    if (tid < 8) sGB[tid] = gB[tid];
    __syncthreads();

    const int n = blockIdx.x*256 + tid;
    const int s = n & (S_-1), h = (n >> 10) & (NH_-1), b = n >> 14;
    const size_t po = ((size_t)(b*S_ + s)*NH_ + h)*64;

    float lg[8];
    #pragma unroll
    for (int e = 0; e < 8; e++) lg[e] = sGB[e];

    for (int dc = 0; dc < 16; dc++){
        float4 x4 = ((const float4*)(x_src + po))[dc];
        float xv[4] = {x4.x, x4.y, x4.z, x4.w};
        #pragma unroll
        for (int i = 0; i < 4; i++){
            const int d = dc*4 + i;
            #pragma unroll
            for (int e = 0; e < 8; e++) lg[e] += sGW[e*64 + d] * xv[i];
        }
    }

    int i1 = 0; float v1 = lg[0];
    #pragma unroll
    for (int e = 1; e < 8; e++){ if (lg[e] > v1){ v1 = lg[e]; i1 = e; } }
    int i2 = -1; float v2 = -3.0e38f;
    #pragma unroll
    for (int e = 0; e < 8; e++){ if (e != i1 && lg[e] > v2){ v2 = lg[e]; i2 = e; } }

    topiv[n] = make_uint4((u32)i1, (u32)i2, __float_as_uint(v1), __float_as_uint(v2));

    const int lane = tid & 63;
    const int w    = tid >> 6;
    #pragma unroll
    for (int e = 0; e < 8; e++){
        u64 m1 = __ballot(i1 == e);
        u64 m2 = __ballot(i2 == e);
        if (lane == 0) sWc[w][e] = (u32)(__popcll(m1) + __popcll(m2));
    }
    __syncthreads();
    if (tid < 8){
        u32 t = sWc[0][tid] + sWc[1][tid] + sWc[2][tid] + sWc[3][tid];
        if (t) atomicAdd(&counts[tid*CSTRIDE], t);
    }
}

// ---------------- kernel 4: scatter into compact per-expert lists (block-aggregated atomics) ----------------
__global__ __launch_bounds__(256,2) void k_scatter(
    const uint4* __restrict__ topiv, const u32* __restrict__ counts, u32* __restrict__ cursors,
    u32* __restrict__ bucket, int2* __restrict__ slots)
{
    __shared__ u32 sC1[4][8], sC2[4][8];   // per-wave counts
    __shared__ u32 sB1[4][8], sB2[4][8];   // per-wave global bases

    const int tid = threadIdx.x;
    const int n = blockIdx.x*256 + tid;
    uint4 t = topiv[n];
    const int i1 = (int)t.x, i2 = (int)t.y;

    int off[8]; int acc = 0;
    #pragma unroll
    for (int e = 0; e < 8; e++){ off[e] = acc; acc += (int)counts[e*CSTRIDE]; }

    const int s = n & (S_-1), h = (n >> 10) & (NH_-1), b = n >> 14;
    const u32 pos32 = (u32)((b*S_ + s)*NH_ + h);

    const int lane = tid & 63;
    const int w    = tid >> 6;
    const u64 low = (1ull << lane) - 1ull;

    u64 myM1 = 0, myM2 = 0;
    #pragma unroll
    for (int e = 0; e < 8; e++){
        u64 m1 = __ballot(i1 == e);
        u64 m2 = __ballot(i2 == e);
        if (i1 == e) myM1 = m1;
        if (i2 == e) myM2 = m2;
        if (lane == 0){ sC1[w][e] = (u32)__popcll(m1); sC2[w][e] = (u32)__popcll(m2); }
    }
    __syncthreads();

    if (tid < 8){
        const int e = tid;
        u32 tot = 0;
        #pragma unroll
        for (int ww = 0; ww < 4; ww++) tot += sC1[ww][e] + sC2[ww][e];
        u32 base = tot ? atomicAdd(&cursors[e*CSTRIDE], tot) : 0;
        u32 run = base;
        #pragma unroll
        for (int ww = 0; ww < 4; ww++){
            sB1[ww][e] = run; run += sC1[ww][e];
            sB2[ww][e] = run; run += sC2[ww][e];
        }
    }
    __syncthreads();

    const int slot1 = off[i1] + (int)sB1[w][i1] + (int)__popcll(myM1 & low);
    const int slot2 = off[i2] + (int)sB2[w][i2] + (int)__popcll(myM2 & low);

    bucket[slot1] = pos32;
    bucket[slot2] = pos32;
    slots[n] = make_int2(slot1, slot2);
}

// ---------------- kernel 5 (MFMA): compacted expert FFN — XOR-swizzled pow2 LDS, 3 blocks/CU ----------------
// Swizzle: byte_off ^= ((row&7)<<4) on both tiles, applied identically at every access.
// All accesses are within-row; XOR touches byte bits 4-6 only -> preserves 16B/8B/2B alignment.
__global__ __launch_bounds__(256,3) void k_expert_mfma(
    const float* __restrict__ x_src, const u32* __restrict__ bucket, const u32* __restrict__ counts,
    const u16* __restrict__ wB1, const u16* __restrict__ wB2,
    const float* __restrict__ l1g, const float* __restrict__ l1b,
    const float* __restrict__ l2g, const float* __restrict__ l2b,
    const float* __restrict__ b2,  u16* __restrict__ aout)
{
    const int e = blockIdx.x >> 10;
    const int c = blockIdx.x & 1023;
    const int cnt = (int)counts[e*CSTRIDE];
    const int aBase = c * 128;
    if (aBase >= cnt) return;     // block-uniform, before any barrier

    int off = 0;
    #pragma unroll
    for (int ee = 0; ee < 8; ee++){ if (ee < e) off += (int)counts[ee*CSTRIDE]; }

    __shared__ __align__(16) u16 sA1[128*64];    // row stride 128B; gelu(LN1(x)); reused as out tile
    __shared__ __align__(16) u16 sH [128*128];   // row stride 256B; gelu(LN2(H))
    __shared__ float2 sStat[2*128];              // per-row partial {sum,sumsq} per n-half
    __shared__ u32   sPos[128];
    __shared__ float sL1g[64], sL1b[64], sL2g[128], sL2b[128], sB2[64];

    const int tid = threadIdx.x;
    if (tid < 64){ sL1g[tid] = l1g[e*64+tid]; sL1b[tid] = l1b[e*64+tid]; sB2[tid] = b2[e*64+tid]; }
    else if (tid < 192){ int t = tid - 64; sL2g[t] = l2g[e*128+t]; sL2b[t] = l2b[e*128+t]; }
    if (tid < 128){
        int a = aBase + tid; if (a > cnt-1) a = cnt-1;   // clamp tail: duplicate last token
        sPos[tid] = bucket[off + a];
    }
    __syncthreads();

    // ---- phase 1: gather x, LN1, gelu, stage bf16 (16 lanes per token) ----
    {
        const int q = tid & 15;
        #pragma unroll
        for (int it = 0; it < 8; it++){
            const int tok = it*16 + (tid >> 4);
            const u32 pos = sPos[tok];
            float4 x4 = *(const float4*)(x_src + ((size_t)pos << 6) + q*4);
            float s0 = x4.x + x4.y + x4.z + x4.w;
            float s1 = x4.x*x4.x + x4.y*x4.y + x4.z*x4.z + x4.w*x4.w;
            #pragma unroll
            for (int msk = 1; msk < 16; msk <<= 1){
                s0 += __shfl_xor(s0, msk);
                s1 += __shfl_xor(s1, msk);
            }
            const float mu = s0 * (1.0f/64.0f);
            const float rs = rsqrtf(s1 * (1.0f/64.0f) - mu*mu + 1e-5f);
            s16x4 pk;
            pk[0] = (short)f2bf(gelu_f((x4.x - mu)*rs*sL1g[q*4+0] + sL1b[q*4+0]));
            pk[1] = (short)f2bf(gelu_f((x4.y - mu)*rs*sL1g[q*4+1] + sL1b[q*4+1]));
            pk[2] = (short)f2bf(gelu_f((x4.z - mu)*rs*sL1g[q*4+2] + sL1b[q*4+2]));
            pk[3] = (short)f2bf(gelu_f((x4.w - mu)*rs*sL1g[q*4+3] + sL1b[q*4+3]));
            *(s16x4*)((char*)sA1 + (((tok<<7) + (q<<3)) ^ ((tok&7)<<4))) = pk;
        }
    }
    __syncthreads();

    // ---- phase 2: GEMM1  H[128x128] = A1[128x64] @ W1^T ----
    const int lane = tid & 63;
    const int w    = tid >> 6;
    const int m    = lane & 15;
    const int kg   = lane >> 4;
    const int th   = w >> 1;        // token half (64 rows)
    const int nh   = w & 1;         // n half (64 cols)

    f32x4 acc[4][4];
    const f32x4 z = {0.f,0.f,0.f,0.f};
    #pragma unroll
    for (int i=0;i<4;i++){ acc[i][0]=z;acc[i][1]=z;acc[i][2]=z;acc[i][3]=z; }

    const u16* wB1e = wB1 + e*8192;
    #pragma unroll
    for (int kk = 0; kk < 2; kk++){
        const int k0 = kk*32 + kg*8;
        short8 aF[4], bF[4];
        #pragma unroll
        for (int mt = 0; mt < 4; mt++){
            const int row = th*64 + mt*16 + m;
            aF[mt] = *(const short8*)((const char*)sA1 + (((row<<7) + (k0<<1)) ^ ((row&7)<<4)));
        }
        #pragma unroll
        for (int ct = 0; ct < 4; ct++)
            bF[ct] = *(const short8*)(wB1e + (nh*64 + ct*16 + m)*64 + k0);
        #pragma unroll
        for (int mt = 0; mt < 4; mt++)
            #pragma unroll
            for (int ct = 0; ct < 4; ct++)
                acc[mt][ct] = __builtin_amdgcn_mfma_f32_16x16x32_bf16(aF[mt], bF[ct], acc[mt][ct], 0,0,0);
    }

    // ---- phase 3: LN2 stats — per-row partials over this wave's 64 cols ----
    #pragma unroll
    for (int mt = 0; mt < 4; mt++){
        #pragma unroll
        for (int r = 0; r < 4; r++){
            float v0 = acc[mt][0][r], v1 = acc[mt][1][r], v2 = acc[mt][2][r], v3 = acc[mt][3][r];
            float p0 = (v0+v1)+(v2+v3);
            float p1 = (v0*v0+v1*v1)+(v2*v2+v3*v3);
            #pragma unroll
            for (int msk = 1; msk < 16; msk <<= 1){
                p0 += __shfl_xor(p0, msk);
                p1 += __shfl_xor(p1, msk);
            }
            if (m == 0){
                const int row = th*64 + mt*16 + kg*4 + r;
                sStat[nh*128 + row] = make_float2(p0, p1);
            }
        }
    }
    __syncthreads();

    // ---- phase 4: gelu(LN2(H)) -> sH bf16 (scalar swizzled stores, logical col order) ----
    #pragma unroll
    for (int mt = 0; mt < 4; mt++){
        #pragma unroll
        for (int r = 0; r < 4; r++){
            const int row = th*64 + mt*16 + kg*4 + r;
            const float2 a0 = sStat[row];
            const float2 a1 = sStat[128 + row];
            const float s0 = a0.x + a1.x, s1 = a0.y + a1.y;
            const float mu = s0 * (1.0f/128.0f);
            const float rs = rsqrtf(s1 * (1.0f/128.0f) - mu*mu + 1e-5f);
            #pragma unroll
            for (int ct = 0; ct < 4; ct++){
                const int col = nh*64 + ct*16 + m;
                *(u16*)((char*)sH + (((row<<8) + (col<<1)) ^ ((row&7)<<4)))
                    = f2bf(gelu_f((acc[mt][ct][r] - mu)*rs*sL2g[col] + sL2b[col]));
            }
        }
    }
    __syncthreads();

    // ---- phase 5: GEMM2  OUT[128x64] = H[128x128] @ W2^T ----
    f32x4 acc2[2][4];
    #pragma unroll
    for (int i=0;i<2;i++){ acc2[i][0]=z;acc2[i][1]=z;acc2[i][2]=z;acc2[i][3]=z; }

    const u16* wB2e = wB2 + e*8192;
    #pragma unroll
    for (int kk = 0; kk < 4; kk++){
        const int k0 = kk*32 + kg*8;
        short8 aF[2], bF[4];
        #pragma unroll
        for (int mt = 0; mt < 2; mt++){
            const int row = w*32 + mt*16 + m;
            aF[mt] = *(const short8*)((const char*)sH + (((row<<8) + (k0<<1)) ^ ((row&7)<<4)));
        }
        #pragma unroll
        for (int ct = 0; ct < 4; ct++)
            bF[ct] = *(const short8*)(wB2e + (ct*16 + m)*128 + k0);
        #pragma unroll
        for (int mt = 0; mt < 2; mt++)
            #pragma unroll
            for (int ct = 0; ct < 4; ct++)
                acc2[mt][ct] = __builtin_amdgcn_mfma_f32_16x16x32_bf16(aF[mt], bF[ct], acc2[mt][ct], 0,0,0);
    }

    // ---- phase 6: +b2, bf16, stage to out tile (sA1 reuse, dead since phase-3 barrier) ----
    #pragma unroll
    for (int mt = 0; mt < 2; mt++){
        #pragma unroll
        for (int r = 0; r < 4; r++){
            const int row = w*32 + mt*16 + kg*4 + r;
            #pragma unroll
            for (int ct = 0; ct < 4; ct++){
                const int col = ct*16 + m;
                *(u16*)((char*)sA1 + (((row<<7) + (col<<1)) ^ ((row&7)<<4)))
                    = f2bf(acc2[mt][ct][r] + sB2[col]);
            }
        }
    }
    __syncthreads();

    // ---- phase 7: coalesced 16B stores (block's aout rows are contiguous) ----
    #pragma unroll
    for (int it = 0; it < 4; it++){
        const int idx = it*256 + tid;          // 0..1023
        const int row = idx >> 3, qq = idx & 7;
        if (aBase + row < cnt){
            uint4 v = *(const uint4*)((const char*)sA1 + (((row<<7) + (qq<<4)) ^ ((row&7)<<4)));
            *(uint4*)(aout + ((size_t)(off + aBase + row) << 6) + qq*8) = v;
        }
    }
}

// ---------------- kernel 5 (fallback, scalar — used only if ws too small) ----------------
__global__ __launch_bounds__(256,2) void k_expert(
    const float* __restrict__ x_src, const u32* __restrict__ bucket, const u32* __restrict__ counts,
    const float* __restrict__ W1,  const float* __restrict__ W2,
    const float* __restrict__ l1g, const float* __restrict__ l1b,
    const float* __restrict__ l2g, const float* __restrict__ l2b,
    const float* __restrict__ b2,  u16* __restrict__ aout)
{
    const int e = blockIdx.x >> 9;
    const int c = blockIdx.x & 511;
    const int cnt = (int)counts[e*CSTRIDE];
    const int aBase = c * 256;
    if (aBase >= cnt) return;

    int off = 0;
    for (int ee = 0; ee < 8; ee++){ if (ee < e) off += (int)counts[ee*CSTRIDE]; }

    __shared__ float sW1[8192];
    __shared__ float sW2T[128*68];
    __shared__ float sL1g[64], sL1b[64], sL2g[128], sL2b[128], sB2[64];
    const int tid = threadIdx.x;
    for (int i = tid; i < 8192; i += 256){
        sW1[i] = W1[e*8192 + i];
        int d = i >> 7, j = i & 127;
        sW2T[j*68 + d] = W2[e*8192 + i];
    }
    if (tid < 64){ sL1g[tid] = l1g[e*64+tid]; sL1b[tid] = l1b[e*64+tid]; sB2[tid] = b2[e*64+tid]; }
    if (tid < 128){ sL2g[tid] = l2g[e*128+tid]; sL2b[tid] = l2b[e*128+tid]; }
    __syncthreads();

    const int a = aBase + tid;
    if (a >= cnt) return;
    const u32 pos32 = bucket[off + a];

    float g[64];
    #pragma unroll
    for (int i = 0; i < 16; i++){
        float4 t = ((const float4*)(x_src + (size_t)pos32*64))[i];
        g[i*4+0]=t.x; g[i*4+1]=t.y; g[i*4+2]=t.z; g[i*4+3]=t.w;
    }

    float s0 = 0.f, s1 = 0.f;
    #pragma unroll
    for (int d = 0; d < 64; d++){ s0 += g[d]; s1 += g[d]*g[d]; }
    float m  = s0 * (1.0f/64.0f);
    float va = s1 * (1.0f/64.0f) - m*m;
    float rs = rsqrtf(va + 1e-5f);
    #pragma unroll
    for (int d = 0; d < 64; d++) g[d] = gelu_exact((g[d]-m)*rs*sL1g[d] + sL1b[d]);

    u32 hpk[64];
    float hs = 0.f, hs2 = 0.f;
    for (int jp = 0; jp < 64; jp++){
        float h0, h1;
        {
            float a0=0.f,a1=0.f,a2=0.f,a3=0.f;
            const float4* w4 = (const float4*)&sW1[(2*jp)*64];
            #pragma unroll
            for (int i = 0; i < 16; i++){
                float4 ww = w4[i];
                a0 += ww.x*g[i*4+0]; a1 += ww.y*g[i*4+1]; a2 += ww.z*g[i*4+2]; a3 += ww.w*g[i*4+3];
            }
            h0 = (a0+a1)+(a2+a3);
        }
        {
            float a0=0.f,a1=0.f,a2=0.f,a3=0.f;
            const float4* w4 = (const float4*)&sW1[(2*jp+1)*64];
            #pragma unroll
            for (int i = 0; i < 16; i++){
                float4 ww = w4[i];
                a0 += ww.x*g[i*4+0]; a1 += ww.y*g[i*4+1]; a2 += ww.z*g[i*4+2]; a3 += ww.w*g[i*4+3];
            }
            h1 = (a0+a1)+(a2+a3);
        }
        hs += h0 + h1; hs2 += h0*h0 + h1*h1;
        hpk[jp] = (u32)f2bf(h0) | ((u32)f2bf(h1) << 16);
    }
    float m2  = hs  * (1.0f/128.0f);
    float va2 = hs2 * (1.0f/128.0f) - m2*m2;
    float rs2 = rsqrtf(va2 + 1e-5f);

    float acc[64];
    #pragma unroll
    for (int d = 0; d < 64; d++) acc[d] = sB2[d];
    for (int j = 0; j < 128; j++){
        float hj = bf2f((u16)((j & 1) ? (hpk[j>>1] >> 16) : (hpk[j>>1] & 0xffffu)));
        float gh = gelu_exact((hj - m2)*rs2*sL2g[j] + sL2b[j]);
        const float4* w2t = (const float4*)&sW2T[j*68];
        #pragma unroll
        for (int d4 = 0; d4 < 16; d4++){
            float4 w = w2t[d4];
            acc[d4*4+0] += gh * w.x;
            acc[d4*4+1] += gh * w.y;
            acc[d4*4+2] += gh * w.z;
            acc[d4*4+3] += gh * w.w;
        }
    }

    u16* op = aout + (size_t)(off + a) * 64;
    #pragma unroll
    for (int dc = 0; dc < 8; dc++){
        uint4 o;
        o.x = (u32)f2bf(acc[dc*8+0]) | ((u32)f2bf(acc[dc*8+1]) << 16);
        o.y = (u32)f2bf(acc[dc*8+2]) | ((u32)f2bf(acc[dc*8+3]) << 16);
        o.z = (u32)f2bf(acc[dc*8+4]) | ((u32)f2bf(acc[dc*8+5]) << 16);
        o.w = (u32)f2bf(acc[dc*8+6]) | ((u32)f2bf(acc[dc*8+7]) << 16);
        ((uint4*)op)[dc] = o;
    }
}

// ---------------- kernel 6: combine top-2 expert outputs -> out0 (overwrites x) ----------------
__global__ __launch_bounds__(256,4) void k_combine(
    const u16* __restrict__ aout, const uint4* __restrict__ topiv,
    const int2* __restrict__ slots, float* __restrict__ out0)
{
    const int tid = threadIdx.x;
    const int p   = blockIdx.x*16 + (tid >> 4);
    const int cq  = tid & 15;

    const int h  = p & (NH_-1);
    const int bs = p >> 4;
    const int b  = bs >> 10, s = bs & (S_-1);
    const int n  = ((b*NH_ + h) << 10) + s;

    uint4 t = topiv[n];
    float w1 = __uint_as_float(t.z), w2 = __uint_as_float(t.w);
    int2 sl = slots[n];

    uint2 ua = *(const uint2*)(aout + (size_t)sl.x*64 + cq*4);
    uint2 ub = *(const uint2*)(aout + (size_t)sl.y*64 + cq*4);

    float4 o;
    o.x = w1*bf2f((u16)(ua.x & 0xffffu)) + w2*bf2f((u16)(ub.x & 0xffffu));
    o.y = w1*bf2f((u16)(ua.x >> 16))     + w2*bf2f((u16)(ub.x >> 16));
    o.z = w1*bf2f((u16)(ua.y & 0xffffu)) + w2*bf2f((u16)(ub.y & 0xffffu));
    o.w = w1*bf2f((u16)(ua.y >> 16))     + w2*bf2f((u16)(ub.y >> 16));
    *(float4*)(out0 + (size_t)p*64 + cq*4) = o;
}

// ---------------- launch ----------------
extern "C" void kernel_launch(void* const* d_in, const int* in_sizes, int n_in,
                              void* d_out, int out_size, void* d_ws, size_t ws_size,
                              hipStream_t stream)
{
    const float* qin = (const float*)d_in[0];
    const float* kin = (const float*)d_in[1];
    const float* vin = (const float*)d_in[2];
    const float* mem = (const float*)d_in[3];
    const float* Wq  = (const float*)d_in[4];
    const float* Wk  = (const float*)d_in[5];
    const float* Wv  = (const float*)d_in[6];
    const float* fg  = (const float*)d_in[7];
    const float* gW  = (const float*)d_in[8];
    const float* gB  = (const float*)d_in[9];
    const float* l1g = (const float*)d_in[10];
    const float* l1b = (const float*)d_in[11];
    const float* W1  = (const float*)d_in[12];
    const float* l2g = (const float*)d_in[13];
    const float* l2b = (const float*)d_in[14];
    const float* W2  = (const float*)d_in[15];
    const float* b2  = (const float*)d_in[16];

    float* out0 = (float*)d_out;                    // token_mixing [B,S,NH*HD]
    float* out1 = out0 + (size_t)NTOK * 64;         // current_memorys [B,NH,S,HD]

    // ws layout (base 37.75 MB proven; padded counters live in the 1KB gap before wB1)
    char* ws = (char*)d_ws;
    u16*   aout   = (u16*)(ws);                               // 2N*64*2  = 33,554,432
    uint4* topiv  = (uint4*)(ws + (size_t)33554432);          // N*16     =  2,097,152
    int2*  slots  = (int2*)(ws + (size_t)35651584);           // N*8      =  1,048,576
    u32*   bucket = (u32*)(ws + (size_t)36700160);            // 2N*4     =  1,048,576
    u32*   counts = (u32*)(ws + (size_t)37748736);            // 8 * 64B padded = 512B
    u32*   cursors = (u32*)(ws + (size_t)37749248);           // 8 * 64B padded = 512B
    u16*   wB1    = (u16*)(ws + (size_t)37749760);            // 131072 B (bf16 W1)
    u16*   wB2    = (u16*)(ws + (size_t)37880832);            // 131072 B (bf16 W2)
    const size_t WS_NEED = 38011904;

    (void)in_sizes; (void)n_in; (void)out_size;

    const bool use_mfma = (ws_size >= WS_NEED);

    k_zero   <<<1, 256, 0, stream>>>(counts);   // zeroes counts + cursors (256 u32 contiguous)
    if (use_mfma)
        k_prep <<<256, 256, 0, stream>>>(W1, W2, wB1, wB2);
    k_mem    <<<512, 256, 0, stream>>>(kin, vin, mem, Wk, Wv, fg, out1);
    k_q      <<<512, 256, 0, stream>>>(qin, out1, Wq, out0);
    k_gate   <<<NTOK/256, 256, 0, stream>>>(out0, gW, gB, topiv, counts);
    k_scatter<<<NTOK/256, 256, 0, stream>>>(topiv, counts, cursors, bucket, slots);
    if (use_mfma)
        k_expert_mfma<<<E_*1024, 256, 0, stream>>>(out0, bucket, counts, wB1, wB2,
                                                   l1g, l1b, l2g, l2b, b2, aout);
    else
        k_expert <<<E_*512, 256, 0, stream>>>(out0, bucket, counts, W1, W2,
                                              l1g, l1b, l2g, l2b, b2, aout);
    k_combine<<<NTOK/16, 256, 0, stream>>>(aout, topiv, slots, out0);
}

// Round 5
// 326.858 us; speedup vs baseline: 3.6648x; 1.0393x over previous
//
#include <hip/hip_runtime.h>
#include <stdint.h>

typedef unsigned short u16;
typedef unsigned int   u32;
typedef unsigned long long u64;
typedef __attribute__((ext_vector_type(8))) short short8;
typedef __attribute__((ext_vector_type(4))) short s16x4;
typedef __attribute__((ext_vector_type(4))) float f32x4;

#define B_    8
#define S_    1024
#define HID_  1024
#define NH_   16
#define HD_   64
#define E_    8
#define IDIM_ 128
#define NTOK  (B_*NH_*S_)   /* 131072 */

// padded-counter stride: one 64B cacheline per expert
#define CSTRIDE 16

// ---------- helpers ----------
__device__ __forceinline__ float bf2f(u16 u){ return __uint_as_float(((u32)u) << 16); }
__device__ __forceinline__ u16 f2bf(float f){
    u32 u = __float_as_uint(f);
    u32 r = u + 0x7fffu + ((u >> 16) & 1u);   // RNE
    return (u16)(r >> 16);
}
// 8 consecutive fp32 -> bf16 MFMA fragment (A or B operand)
__device__ __forceinline__ short8 frag8(const float* __restrict__ p){
    float4 a = *(const float4*)p;
    float4 b = *(const float4*)(p + 4);
    short8 r;
    r[0]=(short)f2bf(a.x); r[1]=(short)f2bf(a.y); r[2]=(short)f2bf(a.z); r[3]=(short)f2bf(a.w);
    r[4]=(short)f2bf(b.x); r[5]=(short)f2bf(b.y); r[6]=(short)f2bf(b.z); r[7]=(short)f2bf(b.w);
    return r;
}
// exact gelu (kept for scalar fallback path)
__device__ __forceinline__ float gelu_exact(float x){
    return 0.5f * x * (1.0f + erff(x * 0.70710678118654752f));
}
// tanh-form gelu: max abs err ~3e-4 vs exact; short dep chain, uses v_exp_f32
__device__ __forceinline__ float gelu_f(float x){
    float z = 1.5957691216057308f * (x + 0.044715f * x * x * x);   // 2*sqrt(2/pi)*(...)
    float e = __expf(z);                                            // exp(2*z_tanh)
    float t = 1.0f - 2.0f / (e + 1.0f);                             // tanh
    return 0.5f * x * (1.0f + t);
}

// ---------------- kernel 0: zero padded counters (counts 128 u32 + cursors 128 u32) ----------------
__global__ void k_zero(u32* c){
    c[threadIdx.x] = 0;   // launched with 256 threads
}

// ---------------- kernel 0b: fp32 weights -> bf16 (both natural layout) ----------------
__global__ __launch_bounds__(256) void k_prep(
    const float* __restrict__ W1, const float* __restrict__ W2,
    u16* __restrict__ wB1, u16* __restrict__ wB2)
{
    const int i = blockIdx.x*256 + threadIdx.x;   // grid 256 -> 65536
    wB1[i] = f2bf(W1[i]);                         // [e][j=128][d=64]
    wB2[i] = f2bf(W2[i]);                         // [e][n=64][k=128]
}

// ---------------- kernel 1: MFMA k/v projection + memory cell -> current_memorys ----------------
__global__ __launch_bounds__(256,2) void k_mem(
    const float* __restrict__ kin, const float* __restrict__ vin, const float* __restrict__ mem,
    const float* __restrict__ Wk,  const float* __restrict__ Wv,  const float* __restrict__ fg,
    float* __restrict__ cur_out)
{
    const int lane = threadIdx.x & 63;
    const int wid  = threadIdx.x >> 6;
    const int m    = lane & 15;
    const int kg   = lane >> 4;

    const int slab  = blockIdx.x;
    const int chunk = slab & 3, h = (slab >> 2) & 15, b = slab >> 6;
    const int tw    = chunk*256 + wid*64;

    const float* kbase = kin + ((size_t)b*S_)*HID_ + h*64;
    const float* vbase = vin + ((size_t)b*S_)*HID_ + h*64;

    f32x4 accK[4][4], accV[4][4];
    const f32x4 z = {0.f,0.f,0.f,0.f};
    #pragma unroll
    for (int i=0;i<4;i++){ accK[i][0]=z;accK[i][1]=z;accK[i][2]=z;accK[i][3]=z;
                           accV[i][0]=z;accV[i][1]=z;accV[i][2]=z;accV[i][3]=z; }

    #pragma unroll
    for (int kk=0; kk<2; kk++){
        const int k0 = kk*32 + kg*8;
        short8 aF[4], bF[4];
        #pragma unroll
        for (int mt=0; mt<4; mt++) aF[mt] = frag8(kbase + (size_t)(tw + mt*16 + m)*HID_ + k0);
        #pragma unroll
        for (int ct=0; ct<4; ct++) bF[ct] = frag8(Wk + (ct*16 + m)*64 + k0);
        #pragma unroll
        for (int mt=0; mt<4; mt++)
            #pragma unroll
            for (int ct=0; ct<4; ct++)
                accK[mt][ct] = __builtin_amdgcn_mfma_f32_16x16x32_bf16(aF[mt], bF[ct], accK[mt][ct], 0,0,0);
    }
    #pragma unroll
    for (int kk=0; kk<2; kk++){
        const int k0 = kk*32 + kg*8;
        short8 aF[4], bF[4];
        #pragma unroll
        for (int mt=0; mt<4; mt++) aF[mt] = frag8(vbase + (size_t)(tw + mt*16 + m)*HID_ + k0);
        #pragma unroll
        for (int ct=0; ct<4; ct++) bF[ct] = frag8(Wv + (ct*16 + m)*64 + k0);
        #pragma unroll
        for (int mt=0; mt<4; mt++)
            #pragma unroll
            for (int ct=0; ct<4; ct++)
                accV[mt][ct] = __builtin_amdgcn_mfma_f32_16x16x32_bf16(aF[mt], bF[ct], accV[mt][ct], 0,0,0);
    }

    const size_t nb = ((size_t)(b*NH_ + h)) << 10;
    float fgv[4];
    #pragma unroll
    for (int ct=0; ct<4; ct++) fgv[ct] = fg[ct*16 + m];

    #pragma unroll
    for (int mt=0; mt<4; mt++){
        #pragma unroll
        for (int r=0; r<4; r++){
            const int tok = tw + mt*16 + kg*4 + r;
            const size_t rowo = (nb + (size_t)tok)*64;
            #pragma unroll
            for (int ct=0; ct<4; ct++){
                const int d = ct*16 + m;
                const float kd = accK[mt][ct][r];
                const float vd = accV[mt][ct][r];
                const float f  = fgv[ct];
                const float mv = mem[rowo + d];
                const float cell = kd*vd + f*mv;
                cur_out[rowo + d] = (1.0f - f)*cell + f*mv;
            }
        }
    }
}

// ---------------- kernel 2: MFMA q projection; x = q_*cur -> out0 at final pos ----------------
__global__ __launch_bounds__(256,2) void k_q(
    const float* __restrict__ qin, const float* __restrict__ cur_in, const float* __restrict__ Wq,
    float* __restrict__ out0)
{
    const int lane = threadIdx.x & 63;
    const int wid  = threadIdx.x >> 6;
    const int m    = lane & 15;
    const int kg   = lane >> 4;

    const int slab  = blockIdx.x;
    const int chunk = slab & 3, h = (slab >> 2) & 15, b = slab >> 6;
    const int tw    = chunk*256 + wid*64;

    const float* qbase = qin + ((size_t)b*S_)*HID_ + h*64;

    f32x4 accQ[4][4];
    const f32x4 z = {0.f,0.f,0.f,0.f};
    #pragma unroll
    for (int i=0;i<4;i++){ accQ[i][0]=z;accQ[i][1]=z;accQ[i][2]=z;accQ[i][3]=z; }

    #pragma unroll
    for (int kk=0; kk<2; kk++){
        const int k0 = kk*32 + kg*8;
        short8 aF[4], bF[4];
        #pragma unroll
        for (int mt=0; mt<4; mt++) aF[mt] = frag8(qbase + (size_t)(tw + mt*16 + m)*HID_ + k0);
        #pragma unroll
        for (int ct=0; ct<4; ct++) bF[ct] = frag8(Wq + (ct*16 + m)*64 + k0);
        #pragma unroll
        for (int mt=0; mt<4; mt++)
            #pragma unroll
            for (int ct=0; ct<4; ct++)
                accQ[mt][ct] = __builtin_amdgcn_mfma_f32_16x16x32_bf16(aF[mt], bF[ct], accQ[mt][ct], 0,0,0);
    }

    const size_t nb = ((size_t)(b*NH_ + h)) << 10;
    #pragma unroll
    for (int mt=0; mt<4; mt++){
        #pragma unroll
        for (int r=0; r<4; r++){
            const int tok = tw + mt*16 + kg*4 + r;
            const size_t curo = (nb + (size_t)tok)*64;
            const size_t po   = ((size_t)(b*S_ + tok)*NH_ + h)*64;
            #pragma unroll
            for (int ct=0; ct<4; ct++){
                const int d = ct*16 + m;
                out0[po + d] = accQ[mt][ct][r] * cur_in[curo + d];
            }
        }
    }
}

// ---------------- kernel 3: gate logits + top-2 (block-aggregated counts) ----------------
__global__ __launch_bounds__(256,2) void k_gate(
    const float* __restrict__ x_src, const float* __restrict__ gW, const float* __restrict__ gB,
    uint4* __restrict__ topiv, u32* __restrict__ counts)
{
    __shared__ float sGW[512], sGB[8];
    __shared__ u32 sWc[4][8];
    const int tid = threadIdx.x;
    for (int i = tid; i < 512; i += 256) sGW[i] = gW[i];
    if (tid < 8) sGB[tid] = gB[tid];
    __syncthreads();

    const int n = blockIdx.x*256 + tid;
    const int s = n & (S_-1), h = (n >> 10) & (NH_-1), b = n >> 14;
    const size_t po = ((size_t)(b*S_ + s)*NH_ + h)*64;

    float lg[8];
    #pragma unroll
    for (int e = 0; e < 8; e++) lg[e] = sGB[e];

    for (int dc = 0; dc < 16; dc++){
        float4 x4 = ((const float4*)(x_src + po))[dc];
        float xv[4] = {x4.x, x4.y, x4.z, x4.w};
        #pragma unroll
        for (int i = 0; i < 4; i++){
            const int d = dc*4 + i;
            #pragma unroll
            for (int e = 0; e < 8; e++) lg[e] += sGW[e*64 + d] * xv[i];
        }
    }

    int i1 = 0; float v1 = lg[0];
    #pragma unroll
    for (int e = 1; e < 8; e++){ if (lg[e] > v1){ v1 = lg[e]; i1 = e; } }
    int i2 = -1; float v2 = -3.0e38f;
    #pragma unroll
    for (int e = 0; e < 8; e++){ if (e != i1 && lg[e] > v2){ v2 = lg[e]; i2 = e; } }

    topiv[n] = make_uint4((u32)i1, (u32)i2, __float_as_uint(v1), __float_as_uint(v2));

    const int lane = tid & 63;
    const int w    = tid >> 6;
    #pragma unroll
    for (int e = 0; e < 8; e++){
        u64 m1 = __ballot(i1 == e);
        u64 m2 = __ballot(i2 == e);
        if (lane == 0) sWc[w][e] = (u32)(__popcll(m1) + __popcll(m2));
    }
    __syncthreads();
    if (tid < 8){
        u32 t = sWc[0][tid] + sWc[1][tid] + sWc[2][tid] + sWc[3][tid];
        if (t) atomicAdd(&counts[tid*CSTRIDE], t);
    }
}

// ---------------- kernel 4: scatter into compact per-expert lists (block-aggregated atomics) ----------------
__global__ __launch_bounds__(256,2) void k_scatter(
    const uint4* __restrict__ topiv, const u32* __restrict__ counts, u32* __restrict__ cursors,
    u32* __restrict__ bucket, int2* __restrict__ slots)
{
    __shared__ u32 sC1[4][8], sC2[4][8];   // per-wave counts
    __shared__ u32 sB1[4][8], sB2w[4][8];  // per-wave global bases

    const int tid = threadIdx.x;
    const int n = blockIdx.x*256 + tid;
    uint4 t = topiv[n];
    const int i1 = (int)t.x, i2 = (int)t.y;

    int off[8]; int acc = 0;
    #pragma unroll
    for (int e = 0; e < 8; e++){ off[e] = acc; acc += (int)counts[e*CSTRIDE]; }

    const int s = n & (S_-1), h = (n >> 10) & (NH_-1), b = n >> 14;
    const u32 pos32 = (u32)((b*S_ + s)*NH_ + h);

    const int lane = tid & 63;
    const int w    = tid >> 6;
    const u64 low = (1ull << lane) - 1ull;

    u64 myM1 = 0, myM2 = 0;
    #pragma unroll
    for (int e = 0; e < 8; e++){
        u64 m1 = __ballot(i1 == e);
        u64 m2 = __ballot(i2 == e);
        if (i1 == e) myM1 = m1;
        if (i2 == e) myM2 = m2;
        if (lane == 0){ sC1[w][e] = (u32)__popcll(m1); sC2[w][e] = (u32)__popcll(m2); }
    }
    __syncthreads();

    if (tid < 8){
        const int e = tid;
        u32 tot = 0;
        #pragma unroll
        for (int ww = 0; ww < 4; ww++) tot += sC1[ww][e] + sC2[ww][e];
        u32 base = tot ? atomicAdd(&cursors[e*CSTRIDE], tot) : 0;
        u32 run = base;
        #pragma unroll
        for (int ww = 0; ww < 4; ww++){
            sB1[ww][e] = run; run += sC1[ww][e];
            sB2w[ww][e] = run; run += sC2[ww][e];
        }
    }
    __syncthreads();

    const int slot1 = off[i1] + (int)sB1[w][i1] + (int)__popcll(myM1 & low);
    const int slot2 = off[i2] + (int)sB2w[w][i2] + (int)__popcll(myM2 & low);

    bucket[slot1] = pos32;
    bucket[slot2] = pos32;
    slots[n] = make_int2(slot1, slot2);
}

// ---------------- kernel 5 (MFMA): wave-independent expert FFN — 32 tokens/wave, 1 barrier ----------------
// Each wave owns 32 tokens end-to-end: direct global->frag x load + reg LN1 (k_mem pattern),
// GEMM1 full-N per wave (acc[2][8]) -> LN2 reduce over m-lanes only, wave-private 8KB LDS
// transpose for GEMM2 A (DS ops are in-order per wave: no barrier), epilogue via same region.
// Swizzle byte ^= ((row&7)<<4) identical to proven round-4 formulas.
__global__ __launch_bounds__(256,3) void k_expert_mfma(
    const float* __restrict__ x_src, const u32* __restrict__ bucket, const u32* __restrict__ counts,
    const u16* __restrict__ wB1, const u16* __restrict__ wB2,
    const float* __restrict__ l1g, const float* __restrict__ l1b,
    const float* __restrict__ l2g, const float* __restrict__ l2b,
    const float* __restrict__ b2,  u16* __restrict__ aout)
{
    const int e = blockIdx.x >> 10;
    const int c = blockIdx.x & 1023;
    const int cnt = (int)counts[e*CSTRIDE];
    const int aBase = c * 128;
    if (aBase >= cnt) return;     // block-uniform, before any barrier

    int off = 0;
    #pragma unroll
    for (int ee = 0; ee < 8; ee++){ if (ee < e) off += (int)counts[ee*CSTRIDE]; }

    __shared__ __align__(16) u16 sH[4][32*128];   // 8KB per wave (reused for out staging)
    __shared__ float sL1g[64], sL1b[64], sL2g[128], sL2b[128], sB2[64];

    const int tid = threadIdx.x;
    if (tid < 64){ sL1g[tid] = l1g[e*64+tid]; sL1b[tid] = l1b[e*64+tid]; sB2[tid] = b2[e*64+tid]; }
    else if (tid < 192){ int t = tid - 64; sL2g[t] = l2g[e*128+t]; sL2b[t] = l2b[e*128+t]; }
    __syncthreads();   // only barrier in the kernel

    const int lane = tid & 63;
    const int w    = tid >> 6;
    const int m    = lane & 15;
    const int kg   = lane >> 4;
    const int tb   = aBase + w*32;          // wave token base
    char* sHw = (char*)(&sH[w][0]);         // wave-private 8KB

    // ---- bucket positions for this lane's two A-rows ----
    int pos[2];
    #pragma unroll
    for (int t = 0; t < 2; t++){
        int a = tb + t*16 + m; if (a > cnt-1) a = cnt-1;
        pos[t] = (int)bucket[off + a];
    }

    // ---- phase A: x load (global->reg), LN1 over kg-group, gelu, bf16 frags ----
    short8 aF[2][2];   // [tile][kk]
    #pragma unroll
    for (int t = 0; t < 2; t++){
        const float* rp = x_src + ((size_t)(u32)pos[t] << 6);
        float4 v0 = *(const float4*)(rp + kg*8);
        float4 v1 = *(const float4*)(rp + kg*8 + 4);
        float4 v2 = *(const float4*)(rp + 32 + kg*8);
        float4 v3 = *(const float4*)(rp + 32 + kg*8 + 4);
        float s0 = (v0.x+v0.y+v0.z+v0.w) + (v1.x+v1.y+v1.z+v1.w)
                 + (v2.x+v2.y+v2.z+v2.w) + (v3.x+v3.y+v3.z+v3.w);
        float s1 = (v0.x*v0.x+v0.y*v0.y+v0.z*v0.z+v0.w*v0.w)
                 + (v1.x*v1.x+v1.y*v1.y+v1.z*v1.z+v1.w*v1.w)
                 + (v2.x*v2.x+v2.y*v2.y+v2.z*v2.z+v2.w*v2.w)
                 + (v3.x*v3.x+v3.y*v3.y+v3.z*v3.z+v3.w*v3.w);
        s0 += __shfl_xor(s0, 16); s0 += __shfl_xor(s0, 32);
        s1 += __shfl_xor(s1, 16); s1 += __shfl_xor(s1, 32);
        const float mu = s0 * (1.0f/64.0f);
        const float rs = rsqrtf(s1 * (1.0f/64.0f) - mu*mu + 1e-5f);
        float xv[16] = {v0.x,v0.y,v0.z,v0.w, v1.x,v1.y,v1.z,v1.w,
                        v2.x,v2.y,v2.z,v2.w, v3.x,v3.y,v3.z,v3.w};
        #pragma unroll
        for (int kk = 0; kk < 2; kk++){
            short8 f;
            #pragma unroll
            for (int j = 0; j < 8; j++){
                const int k = kk*32 + kg*8 + j;
                f[j] = (short)f2bf(gelu_f((xv[kk*8+j] - mu)*rs*sL1g[k] + sL1b[k]));
            }
            aF[t][kk] = f;
        }
    }

    // ---- GEMM1: H[32x128] = A1[32x64] @ W1^T ----
    const f32x4 z = {0.f,0.f,0.f,0.f};
    f32x4 acc1[2][8];
    #pragma unroll
    for (int t = 0; t < 2; t++)
        #pragma unroll
        for (int ct = 0; ct < 8; ct++) acc1[t][ct] = z;

    const u16* wB1e = wB1 + e*8192;
    #pragma unroll
    for (int kk = 0; kk < 2; kk++){
        const int k0 = kk*32 + kg*8;
        short8 bF[8];
        #pragma unroll
        for (int ct = 0; ct < 8; ct++)
            bF[ct] = *(const short8*)(wB1e + (ct*16 + m)*64 + k0);
        #pragma unroll
        for (int t = 0; t < 2; t++)
            #pragma unroll
            for (int ct = 0; ct < 8; ct++)
                acc1[t][ct] = __builtin_amdgcn_mfma_f32_16x16x32_bf16(aF[t][kk], bF[ct], acc1[t][ct], 0,0,0);
    }

    // ---- LN2 (reduce over m-lanes) + gelu -> wave-private sH (swizzled) ----
    #pragma unroll
    for (int t = 0; t < 2; t++){
        #pragma unroll
        for (int r = 0; r < 4; r++){
            float p0 = 0.f, p1 = 0.f;
            #pragma unroll
            for (int ct = 0; ct < 8; ct++){ float v = acc1[t][ct][r]; p0 += v; p1 += v*v; }
            #pragma unroll
            for (int msk = 1; msk < 16; msk <<= 1){
                p0 += __shfl_xor(p0, msk);
                p1 += __shfl_xor(p1, msk);
            }
            const float mu = p0 * (1.0f/128.0f);
            const float rs = rsqrtf(p1 * (1.0f/128.0f) - mu*mu + 1e-5f);
            const int row = t*16 + kg*4 + r;           // local row 0..31
            #pragma unroll
            for (int ct = 0; ct < 8; ct++){
                const int col = ct*16 + m;
                *(u16*)(sHw + (((row<<8) + (col<<1)) ^ ((row&7)<<4)))
                    = f2bf(gelu_f((acc1[t][ct][r] - mu)*rs*sL2g[col] + sL2b[col]));
            }
        }
    }
    // DS ops are in-order within a wave: reads below observe the writes above.

    // ---- GEMM2: OUT[32x64] = H[32x128] @ W2^T ----
    f32x4 acc2[2][4];
    #pragma unroll
    for (int t = 0; t < 2; t++)
        #pragma unroll
        for (int ct = 0; ct < 4; ct++) acc2[t][ct] = z;

    const u16* wB2e = wB2 + e*8192;
    #pragma unroll
    for (int kk = 0; kk < 4; kk++){
        const int k0 = kk*32 + kg*8;
        short8 aF2[2], bF2[4];
        #pragma unroll
        for (int t = 0; t < 2; t++){
            const int row = t*16 + m;
            aF2[t] = *(const short8*)(sHw + (((row<<8) + (k0<<1)) ^ ((row&7)<<4)));
        }
        #pragma unroll
        for (int ct = 0; ct < 4; ct++)
            bF2[ct] = *(const short8*)(wB2e + (ct*16 + m)*128 + k0);
        #pragma unroll
        for (int t = 0; t < 2; t++)
            #pragma unroll
            for (int ct = 0; ct < 4; ct++)
                acc2[t][ct] = __builtin_amdgcn_mfma_f32_16x16x32_bf16(aF2[t], bF2[ct], acc2[t][ct], 0,0,0);
    }

    // ---- epilogue: +b2 -> bf16 -> wave LDS out tile (row stride 128B, same swizzle) ----
    #pragma unroll
    for (int t = 0; t < 2; t++){
        #pragma unroll
        for (int r = 0; r < 4; r++){
            const int row = t*16 + kg*4 + r;
            #pragma unroll
            for (int ct = 0; ct < 4; ct++){
                const int col = ct*16 + m;
                *(u16*)(sHw + (((row<<7) + (col<<1)) ^ ((row&7)<<4)))
                    = f2bf(acc2[t][ct][r] + sB2[col]);
            }
        }
    }

    // ---- coalesced 16B stores (wave's aout rows contiguous) ----
    #pragma unroll
    for (int it = 0; it < 4; it++){
        const int idx = it*64 + lane;          // 0..255
        const int row = idx >> 3, qq = idx & 7;
        if (tb + row < cnt){
            uint4 v = *(const uint4*)(sHw + (((row<<7) + (qq<<4)) ^ ((row&7)<<4)));
            *(uint4*)(aout + ((size_t)(off + tb + row) << 6) + qq*8) = v;
        }
    }
}

// ---------------- kernel 5 (fallback, scalar — used only if ws too small) ----------------
__global__ __launch_bounds__(256,2) void k_expert(
    const float* __restrict__ x_src, const u32* __restrict__ bucket, const u32* __restrict__ counts,
    const float* __restrict__ W1,  const float* __restrict__ W2,
    const float* __restrict__ l1g, const float* __restrict__ l1b,
    const float* __restrict__ l2g, const float* __restrict__ l2b,
    const float* __restrict__ b2,  u16* __restrict__ aout)
{
    const int e = blockIdx.x >> 9;
    const int c = blockIdx.x & 511;
    const int cnt = (int)counts[e*CSTRIDE];
    const int aBase = c * 256;
    if (aBase >= cnt) return;

    int off = 0;
    for (int ee = 0; ee < 8; ee++){ if (ee < e) off += (int)counts[ee*CSTRIDE]; }

    __shared__ float sW1[8192];
    __shared__ float sW2T[128*68];
    __shared__ float sL1g[64], sL1b[64], sL2g[128], sL2b[128], sB2[64];
    const int tid = threadIdx.x;
    for (int i = tid; i < 8192; i += 256){
        sW1[i] = W1[e*8192 + i];
        int d = i >> 7, j = i & 127;
        sW2T[j*68 + d] = W2[e*8192 + i];
    }
    if (tid < 64){ sL1g[tid] = l1g[e*64+tid]; sL1b[tid] = l1b[e*64+tid]; sB2[tid] = b2[e*64+tid]; }
    if (tid < 128){ sL2g[tid] = l2g[e*128+tid]; sL2b[tid] = l2b[e*128+tid]; }
    __syncthreads();

    const int a = aBase + tid;
    if (a >= cnt) return;
    const u32 pos32 = bucket[off + a];

    float g[64];
    #pragma unroll
    for (int i = 0; i < 16; i++){
        float4 t = ((const float4*)(x_src + (size_t)pos32*64))[i];
        g[i*4+0]=t.x; g[i*4+1]=t.y; g[i*4+2]=t.z; g[i*4+3]=t.w;
    }

    float s0 = 0.f, s1 = 0.f;
    #pragma unroll
    for (int d = 0; d < 64; d++){ s0 += g[d]; s1 += g[d]*g[d]; }
    float m  = s0 * (1.0f/64.0f);
    float va = s1 * (1.0f/64.0f) - m*m;
    float rs = rsqrtf(va + 1e-5f);
    #pragma unroll
    for (int d = 0; d < 64; d++) g[d] = gelu_exact((g[d]-m)*rs*sL1g[d] + sL1b[d]);

    u32 hpk[64];
    float hs = 0.f, hs2 = 0.f;
    for (int jp = 0; jp < 64; jp++){
        float h0, h1;
        {
            float a0=0.f,a1=0.f,a2=0.f,a3=0.f;
            const float4* w4 = (const float4*)&sW1[(2*jp)*64];
            #pragma unroll
            for (int i = 0; i < 16; i++){
                float4 ww = w4[i];
                a0 += ww.x*g[i*4+0]; a1 += ww.y*g[i*4+1]; a2 += ww.z*g[i*4+2]; a3 += ww.w*g[i*4+3];
            }
            h0 = (a0+a1)+(a2+a3);
        }
        {
            float a0=0.f,a1=0.f,a2=0.f,a3=0.f;
            const float4* w4 = (const float4*)&sW1[(2*jp+1)*64];
            #pragma unroll
            for (int i = 0; i < 16; i++){
                float4 ww = w4[i];
                a0 += ww.x*g[i*4+0]; a1 += ww.y*g[i*4+1]; a2 += ww.z*g[i*4+2]; a3 += ww.w*g[i*4+3];
            }
            h1 = (a0+a1)+(a2+a3);
        }
        hs += h0 + h1; hs2 += h0*h0 + h1*h1;
        hpk[jp] = (u32)f2bf(h0) | ((u32)f2bf(h1) << 16);
    }
    float m2  = hs  * (1.0f/128.0f);
    float va2 = hs2 * (1.0f/128.0f) - m2*m2;
    float rs2 = rsqrtf(va2 + 1e-5f);

    float acc[64];
    #pragma unroll
    for (int d = 0; d < 64; d++) acc[d] = sB2[d];
    for (int j = 0; j < 128; j++){
        float hj = bf2f((u16)((j & 1) ? (hpk[j>>1] >> 16) : (hpk[j>>1] & 0xffffu)));
        float gh = gelu_exact((hj - m2)*rs2*sL2g[j] + sL2b[j]);
        const float4* w2t = (const float4*)&sW2T[j*68];
        #pragma unroll
        for (int d4 = 0; d4 < 16; d4++){
            float4 w = w2t[d4];
            acc[d4*4+0] += gh * w.x;
            acc[d4*4+1] += gh * w.y;
            acc[d4*4+2] += gh * w.z;
            acc[d4*4+3] += gh * w.w;
        }
    }

    u16* op = aout + (size_t)(off + a) * 64;
    #pragma unroll
    for (int dc = 0; dc < 8; dc++){
        uint4 o;
        o.x = (u32)f2bf(acc[dc*8+0]) | ((u32)f2bf(acc[dc*8+1]) << 16);
        o.y = (u32)f2bf(acc[dc*8+2]) | ((u32)f2bf(acc[dc*8+3]) << 16);
        o.z = (u32)f2bf(acc[dc*8+4]) | ((u32)f2bf(acc[dc*8+5]) << 16);
        o.w = (u32)f2bf(acc[dc*8+6]) | ((u32)f2bf(acc[dc*8+7]) << 16);
        ((uint4*)op)[dc] = o;
    }
}

// ---------------- kernel 6: combine top-2 expert outputs -> out0 (overwrites x) ----------------
__global__ __launch_bounds__(256,4) void k_combine(
    const u16* __restrict__ aout, const uint4* __restrict__ topiv,
    const int2* __restrict__ slots, float* __restrict__ out0)
{
    const int tid = threadIdx.x;
    const int p   = blockIdx.x*16 + (tid >> 4);
    const int cq  = tid & 15;

    const int h  = p & (NH_-1);
    const int bs = p >> 4;
    const int b  = bs >> 10, s = bs & (S_-1);
    const int n  = ((b*NH_ + h) << 10) + s;

    uint4 t = topiv[n];
    float w1 = __uint_as_float(t.z), w2 = __uint_as_float(t.w);
    int2 sl = slots[n];

    uint2 ua = *(const uint2*)(aout + (size_t)sl.x*64 + cq*4);
    uint2 ub = *(const uint2*)(aout + (size_t)sl.y*64 + cq*4);

    float4 o;
    o.x = w1*bf2f((u16)(ua.x & 0xffffu)) + w2*bf2f((u16)(ub.x & 0xffffu));
    o.y = w1*bf2f((u16)(ua.x >> 16))     + w2*bf2f((u16)(ub.x >> 16));
    o.z = w1*bf2f((u16)(ua.y & 0xffffu)) + w2*bf2f((u16)(ub.y & 0xffffu));
    o.w = w1*bf2f((u16)(ua.y >> 16))     + w2*bf2f((u16)(ub.y >> 16));
    *(float4*)(out0 + (size_t)p*64 + cq*4) = o;
}

// ---------------- launch ----------------
extern "C" void kernel_launch(void* const* d_in, const int* in_sizes, int n_in,
                              void* d_out, int out_size, void* d_ws, size_t ws_size,
                              hipStream_t stream)
{
    const float* qin = (const float*)d_in[0];
    const float* kin = (const float*)d_in[1];
    const float* vin = (const float*)d_in[2];
    const float* mem = (const float*)d_in[3];
    const float* Wq  = (const float*)d_in[4];
    const float* Wk  = (const float*)d_in[5];
    const float* Wv  = (const float*)d_in[6];
    const float* fg  = (const float*)d_in[7];
    const float* gW  = (const float*)d_in[8];
    const float* gB  = (const float*)d_in[9];
    const float* l1g = (const float*)d_in[10];
    const float* l1b = (const float*)d_in[11];
    const float* W1  = (const float*)d_in[12];
    const float* l2g = (const float*)d_in[13];
    const float* l2b = (const float*)d_in[14];
    const float* W2  = (const float*)d_in[15];
    const float* b2  = (const float*)d_in[16];

    float* out0 = (float*)d_out;                    // token_mixing [B,S,NH*HD]
    float* out1 = out0 + (size_t)NTOK * 64;         // current_memorys [B,NH,S,HD]

    // ws layout (base 37.75 MB proven; padded counters live in the 1KB gap before wB1)
    char* ws = (char*)d_ws;
    u16*   aout   = (u16*)(ws);                               // 2N*64*2  = 33,554,432
    uint4* topiv  = (uint4*)(ws + (size_t)33554432);          // N*16     =  2,097,152
    int2*  slots  = (int2*)(ws + (size_t)35651584);           // N*8      =  1,048,576
    u32*   bucket = (u32*)(ws + (size_t)36700160);            // 2N*4     =  1,048,576
    u32*   counts = (u32*)(ws + (size_t)37748736);            // 8 * 64B padded = 512B
    u32*   cursors = (u32*)(ws + (size_t)37749248);           // 8 * 64B padded = 512B
    u16*   wB1    = (u16*)(ws + (size_t)37749760);            // 131072 B (bf16 W1)
    u16*   wB2    = (u16*)(ws + (size_t)37880832);            // 131072 B (bf16 W2)
    const size_t WS_NEED = 38011904;

    (void)in_sizes; (void)n_in; (void)out_size;

    const bool use_mfma = (ws_size >= WS_NEED);

    k_zero   <<<1, 256, 0, stream>>>(counts);   // zeroes counts + cursors (256 u32 contiguous)
    if (use_mfma)
        k_prep <<<256, 256, 0, stream>>>(W1, W2, wB1, wB2);
    k_mem    <<<512, 256, 0, stream>>>(kin, vin, mem, Wk, Wv, fg, out1);
    k_q      <<<512, 256, 0, stream>>>(qin, out1, Wq, out0);
    k_gate   <<<NTOK/256, 256, 0, stream>>>(out0, gW, gB, topiv, counts);
    k_scatter<<<NTOK/256, 256, 0, stream>>>(topiv, counts, cursors, bucket, slots);
    if (use_mfma)
        k_expert_mfma<<<E_*1024, 256, 0, stream>>>(out0, bucket, counts, wB1, wB2,
                                                   l1g, l1b, l2g, l2b, b2, aout);
    else
        k_expert <<<E_*512, 256, 0, stream>>>(out0, bucket, counts, W1, W2,
                                              l1g, l1b, l2g, l2b, b2, aout);
    k_combine<<<NTOK/16, 256, 0, stream>>>(aout, topiv, slots, out0);
}